// Round 1
// baseline (332.428 us; speedup 1.0000x reference)
//
#include <hip/hip_runtime.h>

#define NN 10000     // nodes
#define NE 640000    // edges
#define NG 64        // graphs
#define NF 128       // feature dim (both layers)
#define NC 10        // classes
#define TMR 16       // gemm row tile
#define TKC 32       // gemm k chunk
#define NB 250       // dst buckets (40 nodes each)
#define BSZ 40       // nodes per bucket
#define G1 512       // blocks in prep pass (2 blocks/CU)
#define ECHUNK 1250  // edges per block (G1*ECHUNK == NE)
#define CAP 32       // ebuf slots per (bucket, block); mean 5, P(>32) ~ 5e-12
#define CCAP 4096    // csrc entries per bucket; mean 2560, +30 sigma

// ---------------- ws layout (bytes) ----------------
// 0        coff    (10000 int)            40000
// 40000    deg     (10000 int)            40000
// 80000    dinv    (10000 f32)            40000
// 120000   gcnt    (64 int)               256
// 120256   done    (1 int + pad)          64
// 120320   pooled  (64*128 f32)           32768
// 153088   csrc    (250*4096 ushort)      2048000
// 2201088  bh      (250*512 int, 512KB) | Gb (10000*128 bf16, 2.56MB)  [bh dead after csr]
// 4761088  ebuf    (128000*32 int, 16.4MB) | bufB (10000*128 f32, 5.12MB) [ebuf dead after csr]
// total ~21.1 MB of the 256 MiB ws. Fixed-capacity slots -> no scans, no
// global-atomic reservation, no pre-zeroing for the bucket pass. pooled/
// gcnt/done are zeroed by k_prep block 0 (stream-ordered before gather2).

__device__ __forceinline__ unsigned short f2bf(float f) {   // RNE
    unsigned int u = __float_as_uint(f);
    return (unsigned short)((u + 0x7FFF + ((u >> 16) & 1)) >> 16);
}
__device__ __forceinline__ float bf_lo(unsigned int p) {
    return __uint_as_float(p << 16);
}
__device__ __forceinline__ float bf_hi(unsigned int p) {
    return __uint_as_float(p & 0xFFFF0000u);
}

// Wave-uniform detection of int64 vs int32 index buffers. For little-endian
// int64, every odd 32-bit word is the (always-zero here) high half.
__device__ __forceinline__ int detect64(const int* w, long span) {
    int lane = threadIdx.x & 63;
    long e = (long)lane * (span - 1) / 63;
    return (__ballot(w[2 * e + 1] != 0) == 0ULL) ? 1 : 0;
}

__device__ __forceinline__ int ld_idx(const void* p, long i, int is64) {
    return is64 ? (int)((const long long*)p)[i] : ((const int*)p)[i];
}

// Fused hist + scatter: per-block LDS histogram over its edge chunk, then
// scatter into fixed-capacity per-(bucket,block) slot ranges of ebuf.
// bh[b*G1+blk] = count (clamped to CAP). Block 0 also zeroes the pooled/
// gcnt/done accumulators used by the fused gather2+pool kernel.
__global__ __launch_bounds__(256) void k_prep(const void* __restrict__ ei,
                                              int* __restrict__ bh,
                                              int* __restrict__ ebuf,
                                              float* __restrict__ pooled,
                                              int* __restrict__ gcnt,
                                              int* __restrict__ done) {
    int is64 = detect64((const int*)ei, NE);
    __shared__ int hist[256];
    __shared__ int cur[256];
    int tid = threadIdx.x;
    hist[tid] = 0;
    __syncthreads();
    if (blockIdx.x == 0) {             // zero pool accumulators (dead until gather2)
        for (int i = tid; i < NG * NF; i += 256) pooled[i] = 0.f;
        if (tid < NG) gcnt[tid] = 0;
        if (tid == 0) done[0] = 0;
    }
    int e0 = blockIdx.x * ECHUNK, e1 = min(NE, e0 + ECHUNK);
    for (int e = e0 + tid; e < e1; e += 256) {
        int dst = ld_idx(ei, (long)NE + e, is64);
        atomicAdd(&hist[dst / BSZ], 1);
    }
    __syncthreads();
    if (tid < NB) {
        int h = hist[tid];
        bh[tid * G1 + blockIdx.x] = min(h, CAP);
        cur[tid] = (tid * G1 + blockIdx.x) * CAP;
    }
    __syncthreads();
    for (int e = e0 + tid; e < e1; e += 256) {
        int dst = ld_idx(ei, (long)NE + e, is64);
        int src = ld_idx(ei, (long)e, is64);
        int b = dst / BSZ;
        int p = atomicAdd(&cur[b], 1);
        int lim = (b * G1 + blockIdx.x) * CAP + CAP;
        if (p < lim) ebuf[p] = ((dst - b * BSZ) << 14) | src;
    }
}

// One block per bucket: count the 40 dsts from the bucket's slot ranges,
// prefix-scan serially, emit coff/deg/dinv, scatter csrc into the bucket's
// fixed CCAP region.
__global__ __launch_bounds__(256) void k_csr(const int* __restrict__ ebuf,
                                             const int* __restrict__ bh,
                                             int* __restrict__ coff,
                                             int* __restrict__ deg,
                                             float* __restrict__ dinv,
                                             unsigned short* __restrict__ csrc) {
    __shared__ int scnt[G1];
    __shared__ int dcount[BSZ];
    __shared__ int dstart[BSZ];
    __shared__ int cur[BSZ];
    int b = blockIdx.x, tid = threadIdx.x;
    for (int i = tid; i < G1; i += 256) scnt[i] = bh[b * G1 + i];
    if (tid < BSZ) dcount[tid] = 0;
    __syncthreads();
    for (int blk = tid; blk < G1; blk += 256) {
        int c = scnt[blk];
        int base = (b * G1 + blk) * CAP;
        for (int i = 0; i < c; ++i)
            atomicAdd(&dcount[ebuf[base + i] >> 14], 1);
    }
    __syncthreads();
    if (tid == 0) {
        int run = 0;
        for (int i = 0; i < BSZ; ++i) {
            dstart[i] = run; cur[i] = b * CCAP + run; run += dcount[i];
        }
    }
    __syncthreads();
    if (tid < BSZ) {
        coff[b * BSZ + tid] = b * CCAP + dstart[tid];
        deg[b * BSZ + tid] = dcount[tid];
        dinv[b * BSZ + tid] = rsqrtf((float)dcount[tid] + 1.0f);
    }
    __syncthreads();
    for (int blk = tid; blk < G1; blk += 256) {
        int c = scnt[blk];
        int base = (b * G1 + blk) * CAP;
        for (int i = 0; i < c; ++i) {
            int pk = ebuf[base + i];
            int p = atomicAdd(&cur[pk >> 14], 1);
            csrc[p] = (unsigned short)(pk & 16383);
        }
    }
}

// Y(bf16) = (X @ W) * dinv[row]. 625 blocks x (16 rows x 128 cols), 256 thr;
// per-thread 2 rows x 4 cols. (unchanged — tuned in prior session)
__global__ __launch_bounds__(256) void k_gemm(const float* __restrict__ X,
                                              const float* __restrict__ W,
                                              const float* __restrict__ dinv,
                                              unsigned short* __restrict__ Y,
                                              int nrows) {
    __shared__ float sX[TKC * 20];       // [k][m] stride 20, 2.6 KB
    __shared__ float sW[32 * 132];       // 16.9 KB, 32 col-panels of 4
    int tid = threadIdx.x;
    int rg = tid & 7;                    // rows rg*2, rg*2+1
    int cg = tid >> 3;                   // cols cg*4 .. cg*4+3 (0..31)
    int m0 = blockIdx.x * TMR;
    float acc[2][4] = {{0.f}};
    for (int kc = 0; kc < NF / TKC; ++kc) {
        int k0 = kc * TKC;
        if (tid < 128) {                 // stage X^T (16 rows x 32 k)
            int row = tid >> 3, kq = tid & 7;
            int mm = m0 + row; if (mm > nrows - 1) mm = nrows - 1;
            float4 v = *(const float4*)(X + (size_t)mm * NF + k0 + kq * 4);
            sX[(kq * 4 + 0) * 20 + row] = v.x;
            sX[(kq * 4 + 1) * 20 + row] = v.y;
            sX[(kq * 4 + 2) * 20 + row] = v.z;
            sX[(kq * 4 + 3) * 20 + row] = v.w;
        }
#pragma unroll
        for (int j = 0; j < 4; ++j) {    // stage W panels (4 float4 per thread)
            int idx = tid + 256 * j;
            int k = idx >> 5, cq = idx & 31;
            float4 v = *(const float4*)(W + (size_t)(k0 + k) * NF + cq * 4);
            *(float4*)(sW + cq * 132 + k * 4) = v;
        }
        __syncthreads();
#pragma unroll 8
        for (int k = 0; k < TKC; ++k) {
            float2 xf = *(const float2*)(sX + k * 20 + rg * 2);
            float4 wf = *(const float4*)(sW + cg * 132 + k * 4);
            acc[0][0] = fmaf(xf.x, wf.x, acc[0][0]);
            acc[0][1] = fmaf(xf.x, wf.y, acc[0][1]);
            acc[0][2] = fmaf(xf.x, wf.z, acc[0][2]);
            acc[0][3] = fmaf(xf.x, wf.w, acc[0][3]);
            acc[1][0] = fmaf(xf.y, wf.x, acc[1][0]);
            acc[1][1] = fmaf(xf.y, wf.y, acc[1][1]);
            acc[1][2] = fmaf(xf.y, wf.z, acc[1][2]);
            acc[1][3] = fmaf(xf.y, wf.w, acc[1][3]);
        }
        __syncthreads();
    }
#pragma unroll
    for (int r = 0; r < 2; ++r) {
        int m = m0 + rg * 2 + r;
        if (m < nrows) {
            float ds = dinv[m];
            ushort4 h;
            h.x = f2bf(acc[r][0] * ds);
            h.y = f2bf(acc[r][1] * ds);
            h.z = f2bf(acc[r][2] * ds);
            h.w = f2bf(acc[r][3] * ds);
            *(ushort4*)(Y + (size_t)m * NF + cg * 4) = h;
        }
    }
}

// Shared accumulation core: one wave per node, quarter-wave (16 lanes x
// uint4 = full 256B row) per edge, 4-deep unroll, fp32 accumulation.
__device__ __forceinline__ void gacc_node(const unsigned short* __restrict__ G,
                                          const unsigned short* __restrict__ csrc,
                                          int beg, int end, int q, int f,
                                          float a[8]) {
    int e = beg + q;
    for (; e + 12 < end; e += 16) {
        int s0 = csrc[e];
        int s1 = csrc[e + 4];
        int s2 = csrc[e + 8];
        int s3 = csrc[e + 12];
        uint4 p0 = ((const uint4*)(G + (size_t)s0 * NF))[f];
        uint4 p1 = ((const uint4*)(G + (size_t)s1 * NF))[f];
        uint4 p2 = ((const uint4*)(G + (size_t)s2 * NF))[f];
        uint4 p3 = ((const uint4*)(G + (size_t)s3 * NF))[f];
        a[0] += bf_lo(p0.x); a[1] += bf_hi(p0.x); a[2] += bf_lo(p0.y); a[3] += bf_hi(p0.y);
        a[4] += bf_lo(p0.z); a[5] += bf_hi(p0.z); a[6] += bf_lo(p0.w); a[7] += bf_hi(p0.w);
        a[0] += bf_lo(p1.x); a[1] += bf_hi(p1.x); a[2] += bf_lo(p1.y); a[3] += bf_hi(p1.y);
        a[4] += bf_lo(p1.z); a[5] += bf_hi(p1.z); a[6] += bf_lo(p1.w); a[7] += bf_hi(p1.w);
        a[0] += bf_lo(p2.x); a[1] += bf_hi(p2.x); a[2] += bf_lo(p2.y); a[3] += bf_hi(p2.y);
        a[4] += bf_lo(p2.z); a[5] += bf_hi(p2.z); a[6] += bf_lo(p2.w); a[7] += bf_hi(p2.w);
        a[0] += bf_lo(p3.x); a[1] += bf_hi(p3.x); a[2] += bf_lo(p3.y); a[3] += bf_hi(p3.y);
        a[4] += bf_lo(p3.z); a[5] += bf_hi(p3.z); a[6] += bf_lo(p3.w); a[7] += bf_hi(p3.w);
    }
    for (; e < end; e += 4) {
        int s = csrc[e];
        uint4 p = ((const uint4*)(G + (size_t)s * NF))[f];
        a[0] += bf_lo(p.x); a[1] += bf_hi(p.x); a[2] += bf_lo(p.y); a[3] += bf_hi(p.y);
        a[4] += bf_lo(p.z); a[5] += bf_hi(p.z); a[6] += bf_lo(p.w); a[7] += bf_hi(p.w);
    }
#pragma unroll
    for (int j = 0; j < 8; ++j) a[j] += __shfl_xor(a[j], 16);
#pragma unroll
    for (int j = 0; j < 8; ++j) a[j] += __shfl_xor(a[j], 32);
}

// Layer-1 gather: OUT[n] = relu( dinv[n]*( sum_e G[csrc[e]] + G[n] ) + bias ).
__global__ __launch_bounds__(256) void k_gather(const unsigned short* __restrict__ G,
                                                const int* __restrict__ off,
                                                const int* __restrict__ dg,
                                                const unsigned short* __restrict__ csrc,
                                                const float* __restrict__ dinv,
                                                const float* __restrict__ bias,
                                                float* __restrict__ OUT) {
    int wid = threadIdx.x >> 6, lane = threadIdx.x & 63;
    int q = lane >> 4, f = lane & 15;
    int n = blockIdx.x * 4 + wid;
    if (n >= NN) return;
    int beg = off[n], end = beg + dg[n];
    float din = dinv[n];
    float a[8] = {0.f, 0.f, 0.f, 0.f, 0.f, 0.f, 0.f, 0.f};
    gacc_node(G, csrc, beg, end, q, f, a);
    if (q == 0) {
        uint4 sp = ((const uint4*)(G + (size_t)n * NF))[f];
        float4 b0 = ((const float4*)bias)[2 * f];
        float4 b1 = ((const float4*)bias)[2 * f + 1];
        float4 o0, o1;
        o0.x = fmaxf(fmaf(din, a[0] + bf_lo(sp.x), b0.x), 0.f);
        o0.y = fmaxf(fmaf(din, a[1] + bf_hi(sp.x), b0.y), 0.f);
        o0.z = fmaxf(fmaf(din, a[2] + bf_lo(sp.y), b0.z), 0.f);
        o0.w = fmaxf(fmaf(din, a[3] + bf_hi(sp.y), b0.w), 0.f);
        o1.x = fmaxf(fmaf(din, a[4] + bf_lo(sp.z), b1.x), 0.f);
        o1.y = fmaxf(fmaf(din, a[5] + bf_hi(sp.z), b1.y), 0.f);
        o1.z = fmaxf(fmaf(din, a[6] + bf_lo(sp.w), b1.z), 0.f);
        o1.w = fmaxf(fmaf(din, a[7] + bf_hi(sp.w), b1.w), 0.f);
        ((float4*)(OUT + (size_t)n * NF))[2 * f] = o0;
        ((float4*)(OUT + (size_t)n * NF))[2 * f + 1] = o1;
    }
}

// Layer-2 gather fused with global-mean-pool + final linear. Node outputs
// never touch HBM: each node's 128 relu'd features are atomicAdd'ed into
// pooled[g][*] (device-scope, cross-XCD coherent). The last-arriving block
// (done counter, fence-release / atomic-load-acquire) computes the 64x10
// final linear: 4 lanes per graph, 32 k's each, shfl-reduced.
__global__ __launch_bounds__(256) void k_gatherpool(const unsigned short* __restrict__ G,
                                                    const int* __restrict__ off,
                                                    const int* __restrict__ dg,
                                                    const unsigned short* __restrict__ csrc,
                                                    const float* __restrict__ dinv,
                                                    const float* __restrict__ bias,
                                                    const void* __restrict__ batch,
                                                    const float* __restrict__ Wl,
                                                    const float* __restrict__ bl,
                                                    float* __restrict__ pooled,
                                                    int* __restrict__ gcnt,
                                                    int* __restrict__ done,
                                                    float* __restrict__ out) {
    int isb64 = detect64((const int*)batch, NN / 2);
    int wid = threadIdx.x >> 6, lane = threadIdx.x & 63;
    int q = lane >> 4, f = lane & 15;
    int n = blockIdx.x * 4 + wid;
    if (n < NN) {
        int beg = off[n], end = beg + dg[n];
        float din = dinv[n];
        float a[8] = {0.f, 0.f, 0.f, 0.f, 0.f, 0.f, 0.f, 0.f};
        gacc_node(G, csrc, beg, end, q, f, a);
        if (q == 0) {
            uint4 sp = ((const uint4*)(G + (size_t)n * NF))[f];
            float4 b0 = ((const float4*)bias)[2 * f];
            float4 b1 = ((const float4*)bias)[2 * f + 1];
            int g = ld_idx(batch, n, isb64);
            float* pg = pooled + (size_t)g * NF + f * 8;
            atomicAdd(pg + 0, fmaxf(fmaf(din, a[0] + bf_lo(sp.x), b0.x), 0.f));
            atomicAdd(pg + 1, fmaxf(fmaf(din, a[1] + bf_hi(sp.x), b0.y), 0.f));
            atomicAdd(pg + 2, fmaxf(fmaf(din, a[2] + bf_lo(sp.y), b0.z), 0.f));
            atomicAdd(pg + 3, fmaxf(fmaf(din, a[3] + bf_hi(sp.y), b0.w), 0.f));
            atomicAdd(pg + 4, fmaxf(fmaf(din, a[4] + bf_lo(sp.z), b1.x), 0.f));
            atomicAdd(pg + 5, fmaxf(fmaf(din, a[5] + bf_hi(sp.z), b1.y), 0.f));
            atomicAdd(pg + 6, fmaxf(fmaf(din, a[6] + bf_lo(sp.w), b1.z), 0.f));
            atomicAdd(pg + 7, fmaxf(fmaf(din, a[7] + bf_hi(sp.w), b1.w), 0.f));
            if (f == 0) atomicAdd(gcnt + g, 1);
        }
    }
    __threadfence();                       // release our pooled adds
    __syncthreads();
    __shared__ int sdone;
    if (threadIdx.x == 0)
        sdone = (atomicAdd(done, 1) == (NN / 4) - 1);
    __syncthreads();
    if (sdone) {                           // last block: pooled/cnt -> out
        int g2 = threadIdx.x >> 2, sub = threadIdx.x & 3;   // 4 lanes per graph
        float acc[NC];
#pragma unroll
        for (int c = 0; c < NC; ++c) acc[c] = 0.f;
        const float* pg = pooled + (size_t)g2 * NF + sub * 32;
#pragma unroll
        for (int ch = 0; ch < 4; ++ch) {
            float v[8];
#pragma unroll
            for (int j = 0; j < 8; ++j)
                v[j] = __hip_atomic_load(pg + ch * 8 + j, __ATOMIC_RELAXED,
                                         __HIP_MEMORY_SCOPE_AGENT);
#pragma unroll
            for (int j = 0; j < 8; ++j) {
                int k = sub * 32 + ch * 8 + j;
#pragma unroll
                for (int c = 0; c < NC; ++c)
                    acc[c] = fmaf(v[j], Wl[k * NC + c], acc[c]);
            }
        }
#pragma unroll
        for (int c = 0; c < NC; ++c) {
            acc[c] += __shfl_xor(acc[c], 1);
            acc[c] += __shfl_xor(acc[c], 2);
        }
        if (sub == 0) {
            int cnt = __hip_atomic_load(gcnt + g2, __ATOMIC_RELAXED,
                                        __HIP_MEMORY_SCOPE_AGENT);
            float ic = 1.0f / fmaxf((float)cnt, 1.0f);
#pragma unroll
            for (int c = 0; c < NC; ++c)
                out[g2 * NC + c] = fmaf(acc[c], ic, bl[c]);
        }
    }
}

extern "C" void kernel_launch(void* const* d_in, const int* in_sizes, int n_in,
                              void* d_out, int out_size, void* d_ws, size_t ws_size,
                              hipStream_t stream) {
    const float* x  = (const float*)d_in[0];
    const void*  ei = d_in[1];
    const void*  bt = d_in[2];
    const float* W1 = (const float*)d_in[3];
    const float* b1 = (const float*)d_in[4];
    const float* W2 = (const float*)d_in[5];
    const float* b2 = (const float*)d_in[6];
    const float* Wl = (const float*)d_in[7];
    const float* bl = (const float*)d_in[8];

    char* ws = (char*)d_ws;
    int*            coff   = (int*)(ws + 0);
    int*            deg    = (int*)(ws + 40000);
    float*          dinv   = (float*)(ws + 80000);
    int*            gcnt   = (int*)(ws + 120000);
    int*            done   = (int*)(ws + 120256);
    float*          pooled = (float*)(ws + 120320);
    unsigned short* csrc   = (unsigned short*)(ws + 153088);
    unsigned short* Gb     = (unsigned short*)(ws + 2201088); // aliases bh (dead after csr)
    float*          bufB   = (float*)(ws + 4761088);          // aliases ebuf (dead after csr)
    int*            bh     = (int*)(ws + 2201088);
    int*            ebuf   = (int*)(ws + 4761088);

    k_prep<<<G1, 256, 0, stream>>>(ei, bh, ebuf, pooled, gcnt, done);
    k_csr <<<NB, 256, 0, stream>>>(ebuf, bh, coff, deg, dinv, csrc);

    k_gemm<<<(NN + TMR - 1) / TMR, 256, 0, stream>>>(x, W1, dinv, Gb, NN);
    k_gather<<<(NN + 3) / 4, 256, 0, stream>>>(Gb, coff, deg, csrc, dinv, b1, bufB);
    k_gemm<<<(NN + TMR - 1) / TMR, 256, 0, stream>>>(bufB, W2, dinv, Gb, NN);
    k_gatherpool<<<(NN + 3) / 4, 256, 0, stream>>>(Gb, coff, deg, csrc, dinv, b2,
                                                   bt, Wl, bl, pooled, gcnt, done,
                                                   (float*)d_out);
}

// Round 2
// 298.350 us; speedup vs baseline: 1.1142x; 1.1142x over previous
//
#include <hip/hip_runtime.h>

#define NN 10000     // nodes
#define NE 640000    // edges
#define NG 64        // graphs
#define NF 128       // feature dim (both layers)
#define NC 10        // classes
#define TMR 16       // gemm row tile
#define TKC 32       // gemm k chunk
#define NB 250       // dst buckets (40 nodes each)
#define BSZ 40       // nodes per bucket
#define G1 512       // blocks in prep pass (2 blocks/CU)
#define ECHUNK 1250  // edges per block (G1*ECHUNK == NE)
#define CAP 32       // ebuf slots per (bucket, block); mean 5, P(>32) ~ 5e-12
#define CCAP 4096    // csrc entries per bucket; mean 2560, +30 sigma

// ---------------- ws layout (bytes) ----------------
// 0        coff    (10000 int)            40000
// 40000    deg     (10000 int)            40000
// 80000    dinv    (10000 f32)            40000
// 120000   outacc  (64*10 f32)            2560   <- pooled@Wl accumulator
// 122560   cntinv  (64 f32)               256    <- 1/nodes-per-graph
// 122816   done    (1 int + pad)          64
// 122880   csrc    (250*4096 ushort)      2048000
// 2201088  bh      (250*512 int, 512KB) | Gb (10000*128 bf16, 2.56MB)  [bh dead after csr]
// 4761088  ebuf    (128000*32 int, 16.4MB) | bufB (10000*128 f32, 5.12MB) [ebuf dead after csr]
//
// Round-1 lesson: device-scope f32 atomics resolve past the XCD L2s at
// ~32B RMW each (measured 40.4MB WRITE_SIZE for 1.28M atomics -> 207us).
// So the pool+linear fusion now reduces per-node to 10 floats IN REGISTERS
// (h @ Wl), combines the block's 4 waves in LDS, and issues ~10 atomics
// per block (25K total, ~0.8MB RMW) into outacc[640].

__device__ __forceinline__ unsigned short f2bf(float f) {   // RNE
    unsigned int u = __float_as_uint(f);
    return (unsigned short)((u + 0x7FFF + ((u >> 16) & 1)) >> 16);
}
__device__ __forceinline__ float bf_lo(unsigned int p) {
    return __uint_as_float(p << 16);
}
__device__ __forceinline__ float bf_hi(unsigned int p) {
    return __uint_as_float(p & 0xFFFF0000u);
}

// Wave-uniform detection of int64 vs int32 index buffers. For little-endian
// int64, every odd 32-bit word is the (always-zero here) high half.
__device__ __forceinline__ int detect64(const int* w, long span) {
    int lane = threadIdx.x & 63;
    long e = (long)lane * (span - 1) / 63;
    return (__ballot(w[2 * e + 1] != 0) == 0ULL) ? 1 : 0;
}

__device__ __forceinline__ int ld_idx(const void* p, long i, int is64) {
    return is64 ? (int)((const long long*)p)[i] : ((const int*)p)[i];
}

// Fused hist + scatter, single pass over the edge stream (dst/src cached in
// registers between the histogram and the scatter). Block 0 zeroes the
// outacc/done accumulators; block 1 wave 0 computes cntinv[g] via 64
// parallel binary searches on the sorted batch vector (overlapped with the
// other 511 blocks' edge work).
__global__ __launch_bounds__(256) void k_prep(const void* __restrict__ ei,
                                              const void* __restrict__ batch,
                                              int* __restrict__ bh,
                                              int* __restrict__ ebuf,
                                              float* __restrict__ outacc,
                                              float* __restrict__ cntinv,
                                              int* __restrict__ done) {
    int is64 = detect64((const int*)ei, NE);
    __shared__ int hist[256];
    __shared__ int cur[256];
    int tid = threadIdx.x;
    hist[tid] = 0;
    __syncthreads();
    if (blockIdx.x == 0) {               // zero pool accumulators
        for (int i = tid; i < NG * NC; i += 256) outacc[i] = 0.f;
        if (tid == 0) done[0] = 0;
    }
    if (blockIdx.x == 1 && tid < NG) {   // cntinv via binary search (wave 0)
        int isb = detect64((const int*)batch, NN / 2);
        int lo0 = 0, hi0 = NN;
        while (lo0 < hi0) {
            int m = (lo0 + hi0) >> 1;
            if (ld_idx(batch, m, isb) < tid) lo0 = m + 1; else hi0 = m;
        }
        int lo1 = lo0, hi1 = NN;
        while (lo1 < hi1) {
            int m = (lo1 + hi1) >> 1;
            if (ld_idx(batch, m, isb) < tid + 1) lo1 = m + 1; else hi1 = m;
        }
        cntinv[tid] = 1.0f / fmaxf((float)(lo1 - lo0), 1.0f);
    }
    int e0 = blockIdx.x * ECHUNK;
    int dstv[5], srcv[5];
#pragma unroll
    for (int i = 0; i < 5; ++i) {
        int r = tid + i * 256;
        if (r < ECHUNK) {
            long e = (long)e0 + r;
            dstv[i] = ld_idx(ei, (long)NE + e, is64);
            srcv[i] = ld_idx(ei, e, is64);
            atomicAdd(&hist[dstv[i] / BSZ], 1);
        } else {
            dstv[i] = -1; srcv[i] = 0;
        }
    }
    __syncthreads();
    if (tid < NB) {
        bh[tid * G1 + blockIdx.x] = min(hist[tid], CAP);
        cur[tid] = (tid * G1 + blockIdx.x) * CAP;
    }
    __syncthreads();
#pragma unroll
    for (int i = 0; i < 5; ++i) {
        if (tid + i * 256 < ECHUNK) {
            int dst = dstv[i], src = srcv[i];
            int b = dst / BSZ;
            int p = atomicAdd(&cur[b], 1);
            int lim = (b * G1 + blockIdx.x) * CAP + CAP;
            if (p < lim) ebuf[p] = ((dst - b * BSZ) << 14) | src;
        }
    }
}

// One block per bucket: count the 40 dsts from the bucket's slot ranges,
// prefix-scan serially, emit coff/deg/dinv, scatter csrc into the bucket's
// fixed CCAP region. (unchanged)
__global__ __launch_bounds__(256) void k_csr(const int* __restrict__ ebuf,
                                             const int* __restrict__ bh,
                                             int* __restrict__ coff,
                                             int* __restrict__ deg,
                                             float* __restrict__ dinv,
                                             unsigned short* __restrict__ csrc) {
    __shared__ int scnt[G1];
    __shared__ int dcount[BSZ];
    __shared__ int dstart[BSZ];
    __shared__ int cur[BSZ];
    int b = blockIdx.x, tid = threadIdx.x;
    for (int i = tid; i < G1; i += 256) scnt[i] = bh[b * G1 + i];
    if (tid < BSZ) dcount[tid] = 0;
    __syncthreads();
    for (int blk = tid; blk < G1; blk += 256) {
        int c = scnt[blk];
        int base = (b * G1 + blk) * CAP;
        for (int i = 0; i < c; ++i)
            atomicAdd(&dcount[ebuf[base + i] >> 14], 1);
    }
    __syncthreads();
    if (tid == 0) {
        int run = 0;
        for (int i = 0; i < BSZ; ++i) {
            dstart[i] = run; cur[i] = b * CCAP + run; run += dcount[i];
        }
    }
    __syncthreads();
    if (tid < BSZ) {
        coff[b * BSZ + tid] = b * CCAP + dstart[tid];
        deg[b * BSZ + tid] = dcount[tid];
        dinv[b * BSZ + tid] = rsqrtf((float)dcount[tid] + 1.0f);
    }
    __syncthreads();
    for (int blk = tid; blk < G1; blk += 256) {
        int c = scnt[blk];
        int base = (b * G1 + blk) * CAP;
        for (int i = 0; i < c; ++i) {
            int pk = ebuf[base + i];
            int p = atomicAdd(&cur[pk >> 14], 1);
            csrc[p] = (unsigned short)(pk & 16383);
        }
    }
}

// Y(bf16) = (X @ W) * dinv[row]. 625 blocks x (16 rows x 128 cols), 256 thr;
// per-thread 2 rows x 4 cols. (unchanged — tuned in prior session)
__global__ __launch_bounds__(256) void k_gemm(const float* __restrict__ X,
                                              const float* __restrict__ W,
                                              const float* __restrict__ dinv,
                                              unsigned short* __restrict__ Y,
                                              int nrows) {
    __shared__ float sX[TKC * 20];       // [k][m] stride 20, 2.6 KB
    __shared__ float sW[32 * 132];       // 16.9 KB, 32 col-panels of 4
    int tid = threadIdx.x;
    int rg = tid & 7;                    // rows rg*2, rg*2+1
    int cg = tid >> 3;                   // cols cg*4 .. cg*4+3 (0..31)
    int m0 = blockIdx.x * TMR;
    float acc[2][4] = {{0.f}};
    for (int kc = 0; kc < NF / TKC; ++kc) {
        int k0 = kc * TKC;
        if (tid < 128) {                 // stage X^T (16 rows x 32 k)
            int row = tid >> 3, kq = tid & 7;
            int mm = m0 + row; if (mm > nrows - 1) mm = nrows - 1;
            float4 v = *(const float4*)(X + (size_t)mm * NF + k0 + kq * 4);
            sX[(kq * 4 + 0) * 20 + row] = v.x;
            sX[(kq * 4 + 1) * 20 + row] = v.y;
            sX[(kq * 4 + 2) * 20 + row] = v.z;
            sX[(kq * 4 + 3) * 20 + row] = v.w;
        }
#pragma unroll
        for (int j = 0; j < 4; ++j) {    // stage W panels (4 float4 per thread)
            int idx = tid + 256 * j;
            int k = idx >> 5, cq = idx & 31;
            float4 v = *(const float4*)(W + (size_t)(k0 + k) * NF + cq * 4);
            *(float4*)(sW + cq * 132 + k * 4) = v;
        }
        __syncthreads();
#pragma unroll 8
        for (int k = 0; k < TKC; ++k) {
            float2 xf = *(const float2*)(sX + k * 20 + rg * 2);
            float4 wf = *(const float4*)(sW + cg * 132 + k * 4);
            acc[0][0] = fmaf(xf.x, wf.x, acc[0][0]);
            acc[0][1] = fmaf(xf.x, wf.y, acc[0][1]);
            acc[0][2] = fmaf(xf.x, wf.z, acc[0][2]);
            acc[0][3] = fmaf(xf.x, wf.w, acc[0][3]);
            acc[1][0] = fmaf(xf.y, wf.x, acc[1][0]);
            acc[1][1] = fmaf(xf.y, wf.y, acc[1][1]);
            acc[1][2] = fmaf(xf.y, wf.z, acc[1][2]);
            acc[1][3] = fmaf(xf.y, wf.w, acc[1][3]);
        }
        __syncthreads();
    }
#pragma unroll
    for (int r = 0; r < 2; ++r) {
        int m = m0 + rg * 2 + r;
        if (m < nrows) {
            float ds = dinv[m];
            ushort4 h;
            h.x = f2bf(acc[r][0] * ds);
            h.y = f2bf(acc[r][1] * ds);
            h.z = f2bf(acc[r][2] * ds);
            h.w = f2bf(acc[r][3] * ds);
            *(ushort4*)(Y + (size_t)m * NF + cg * 4) = h;
        }
    }
}

// Shared accumulation core: one wave per node, quarter-wave (16 lanes x
// uint4 = full 256B row) per edge, 4-deep unroll, fp32 accumulation.
// After the two xor-shuffles ALL 64 lanes hold the reduced sums.
__device__ __forceinline__ void gacc_node(const unsigned short* __restrict__ G,
                                          const unsigned short* __restrict__ csrc,
                                          int beg, int end, int q, int f,
                                          float a[8]) {
    int e = beg + q;
    for (; e + 12 < end; e += 16) {
        int s0 = csrc[e];
        int s1 = csrc[e + 4];
        int s2 = csrc[e + 8];
        int s3 = csrc[e + 12];
        uint4 p0 = ((const uint4*)(G + (size_t)s0 * NF))[f];
        uint4 p1 = ((const uint4*)(G + (size_t)s1 * NF))[f];
        uint4 p2 = ((const uint4*)(G + (size_t)s2 * NF))[f];
        uint4 p3 = ((const uint4*)(G + (size_t)s3 * NF))[f];
        a[0] += bf_lo(p0.x); a[1] += bf_hi(p0.x); a[2] += bf_lo(p0.y); a[3] += bf_hi(p0.y);
        a[4] += bf_lo(p0.z); a[5] += bf_hi(p0.z); a[6] += bf_lo(p0.w); a[7] += bf_hi(p0.w);
        a[0] += bf_lo(p1.x); a[1] += bf_hi(p1.x); a[2] += bf_lo(p1.y); a[3] += bf_hi(p1.y);
        a[4] += bf_lo(p1.z); a[5] += bf_hi(p1.z); a[6] += bf_lo(p1.w); a[7] += bf_hi(p1.w);
        a[0] += bf_lo(p2.x); a[1] += bf_hi(p2.x); a[2] += bf_lo(p2.y); a[3] += bf_hi(p2.y);
        a[4] += bf_lo(p2.z); a[5] += bf_hi(p2.z); a[6] += bf_lo(p2.w); a[7] += bf_hi(p2.w);
        a[0] += bf_lo(p3.x); a[1] += bf_hi(p3.x); a[2] += bf_lo(p3.y); a[3] += bf_hi(p3.y);
        a[4] += bf_lo(p3.z); a[5] += bf_hi(p3.z); a[6] += bf_lo(p3.w); a[7] += bf_hi(p3.w);
    }
    for (; e < end; e += 4) {
        int s = csrc[e];
        uint4 p = ((const uint4*)(G + (size_t)s * NF))[f];
        a[0] += bf_lo(p.x); a[1] += bf_hi(p.x); a[2] += bf_lo(p.y); a[3] += bf_hi(p.y);
        a[4] += bf_lo(p.z); a[5] += bf_hi(p.z); a[6] += bf_lo(p.w); a[7] += bf_hi(p.w);
    }
#pragma unroll
    for (int j = 0; j < 8; ++j) a[j] += __shfl_xor(a[j], 16);
#pragma unroll
    for (int j = 0; j < 8; ++j) a[j] += __shfl_xor(a[j], 32);
}

// Layer-1 gather: OUT[n] = relu( dinv[n]*( sum_e G[csrc[e]] + G[n] ) + bias ).
__global__ __launch_bounds__(256) void k_gather(const unsigned short* __restrict__ G,
                                                const int* __restrict__ off,
                                                const int* __restrict__ dg,
                                                const unsigned short* __restrict__ csrc,
                                                const float* __restrict__ dinv,
                                                const float* __restrict__ bias,
                                                float* __restrict__ OUT) {
    int wid = threadIdx.x >> 6, lane = threadIdx.x & 63;
    int q = lane >> 4, f = lane & 15;
    int n = blockIdx.x * 4 + wid;
    if (n >= NN) return;
    int beg = off[n], end = beg + dg[n];
    float din = dinv[n];
    float a[8] = {0.f, 0.f, 0.f, 0.f, 0.f, 0.f, 0.f, 0.f};
    gacc_node(G, csrc, beg, end, q, f, a);
    if (q == 0) {
        uint4 sp = ((const uint4*)(G + (size_t)n * NF))[f];
        float4 b0 = ((const float4*)bias)[2 * f];
        float4 b1 = ((const float4*)bias)[2 * f + 1];
        float4 o0, o1;
        o0.x = fmaxf(fmaf(din, a[0] + bf_lo(sp.x), b0.x), 0.f);
        o0.y = fmaxf(fmaf(din, a[1] + bf_hi(sp.x), b0.y), 0.f);
        o0.z = fmaxf(fmaf(din, a[2] + bf_lo(sp.y), b0.z), 0.f);
        o0.w = fmaxf(fmaf(din, a[3] + bf_hi(sp.y), b0.w), 0.f);
        o1.x = fmaxf(fmaf(din, a[4] + bf_lo(sp.z), b1.x), 0.f);
        o1.y = fmaxf(fmaf(din, a[5] + bf_hi(sp.z), b1.y), 0.f);
        o1.z = fmaxf(fmaf(din, a[6] + bf_lo(sp.w), b1.z), 0.f);
        o1.w = fmaxf(fmaf(din, a[7] + bf_hi(sp.w), b1.w), 0.f);
        ((float4*)(OUT + (size_t)n * NF))[2 * f] = o0;
        ((float4*)(OUT + (size_t)n * NF))[2 * f + 1] = o1;
    }
}

// Layer-2 gather fused with mean-pool + final linear, REGISTER-reduced:
// each wave computes its node's relu'd h[128] (all 64 lanes hold the
// reduced sums; lane f owns features f*8..f*8+7), multiplies into the
// LDS-staged Wl (128x10) for a 10-float partial, shuffle-reduces over f,
// pre-scales by cntinv[g], combines the block's 4 waves in LDS, and issues
// ~10 global atomics per block (~25K total vs round-1's 1.28M).
// Last-arriving block adds bl and writes d_out.
__global__ __launch_bounds__(256) void k_gatherpool(const unsigned short* __restrict__ G,
                                                    const int* __restrict__ off,
                                                    const int* __restrict__ dg,
                                                    const unsigned short* __restrict__ csrc,
                                                    const float* __restrict__ dinv,
                                                    const float* __restrict__ bias,
                                                    const void* __restrict__ batch,
                                                    const float* __restrict__ Wl,
                                                    const float* __restrict__ bl,
                                                    const float* __restrict__ cntinv,
                                                    float* __restrict__ outacc,
                                                    int* __restrict__ done,
                                                    float* __restrict__ out) {
    __shared__ float sWl[NF * NC];       // 5.1 KB
    __shared__ float wp[4][NC];
    __shared__ int wg[4];
    __shared__ int sdone;
    int tid = threadIdx.x;
    for (int i = tid; i < NF * NC; i += 256) sWl[i] = Wl[i];
    int isb64 = detect64((const int*)batch, NN / 2);
    int wid = tid >> 6, lane = tid & 63;
    int q = lane >> 4, f = lane & 15;
    int n = blockIdx.x * 4 + wid;        // grid is exactly NN/4 -> always valid
    int beg = off[n], end = beg + dg[n];
    float din = dinv[n];
    float a[8] = {0.f, 0.f, 0.f, 0.f, 0.f, 0.f, 0.f, 0.f};
    __syncthreads();                     // sWl ready
    gacc_node(G, csrc, beg, end, q, f, a);
    int g = ld_idx(batch, n, isb64);
    uint4 sp = ((const uint4*)(G + (size_t)n * NF))[f];
    float4 b0 = ((const float4*)bias)[2 * f];
    float4 b1 = ((const float4*)bias)[2 * f + 1];
    float h[8];
    h[0] = fmaxf(fmaf(din, a[0] + bf_lo(sp.x), b0.x), 0.f);
    h[1] = fmaxf(fmaf(din, a[1] + bf_hi(sp.x), b0.y), 0.f);
    h[2] = fmaxf(fmaf(din, a[2] + bf_lo(sp.y), b0.z), 0.f);
    h[3] = fmaxf(fmaf(din, a[3] + bf_hi(sp.y), b0.w), 0.f);
    h[4] = fmaxf(fmaf(din, a[4] + bf_lo(sp.z), b1.x), 0.f);
    h[5] = fmaxf(fmaf(din, a[5] + bf_hi(sp.z), b1.y), 0.f);
    h[6] = fmaxf(fmaf(din, a[6] + bf_lo(sp.w), b1.z), 0.f);
    h[7] = fmaxf(fmaf(din, a[7] + bf_hi(sp.w), b1.w), 0.f);
    float p[NC];
#pragma unroll
    for (int c = 0; c < NC; ++c) p[c] = 0.f;
#pragma unroll
    for (int j = 0; j < 8; ++j) {
        const float* wrow = sWl + (f * 8 + j) * NC;
#pragma unroll
        for (int c = 0; c < NC; ++c) p[c] = fmaf(h[j], wrow[c], p[c]);
    }
#pragma unroll
    for (int c = 0; c < NC; ++c) {       // reduce over f (bits 0..3)
        p[c] += __shfl_xor(p[c], 1);
        p[c] += __shfl_xor(p[c], 2);
        p[c] += __shfl_xor(p[c], 4);
        p[c] += __shfl_xor(p[c], 8);
    }
    if (lane == 0) {
        float ci = cntinv[g];
        wg[wid] = g;
#pragma unroll
        for (int c = 0; c < NC; ++c) wp[wid][c] = p[c] * ci;
    }
    __syncthreads();
    if (tid < 4 * NC) {                  // one atomic per (block, graph, class)
        int w = tid / NC, c = tid - w * NC;
        int gw = wg[w];
        bool first = true;
        for (int w2 = 0; w2 < w; ++w2) if (wg[w2] == gw) first = false;
        if (first) {
            float s = wp[w][c];
            for (int w2 = w + 1; w2 < 4; ++w2) if (wg[w2] == gw) s += wp[w2][c];
            atomicAdd(outacc + gw * NC + c, s);
        }
    }
    __threadfence();                     // release our outacc adds
    __syncthreads();
    if (tid == 0) sdone = (atomicAdd(done, 1) == (NN / 4) - 1);
    __syncthreads();
    if (sdone && tid < NG) {             // last block: outacc + bl -> out
#pragma unroll
        for (int c = 0; c < NC; ++c) {
            float v = __hip_atomic_load(outacc + tid * NC + c, __ATOMIC_RELAXED,
                                        __HIP_MEMORY_SCOPE_AGENT);
            out[tid * NC + c] = v + bl[c];
        }
    }
}

extern "C" void kernel_launch(void* const* d_in, const int* in_sizes, int n_in,
                              void* d_out, int out_size, void* d_ws, size_t ws_size,
                              hipStream_t stream) {
    const float* x  = (const float*)d_in[0];
    const void*  ei = d_in[1];
    const void*  bt = d_in[2];
    const float* W1 = (const float*)d_in[3];
    const float* b1 = (const float*)d_in[4];
    const float* W2 = (const float*)d_in[5];
    const float* b2 = (const float*)d_in[6];
    const float* Wl = (const float*)d_in[7];
    const float* bl = (const float*)d_in[8];

    char* ws = (char*)d_ws;
    int*            coff   = (int*)(ws + 0);
    int*            deg    = (int*)(ws + 40000);
    float*          dinv   = (float*)(ws + 80000);
    float*          outacc = (float*)(ws + 120000);
    float*          cntinv = (float*)(ws + 122560);
    int*            done   = (int*)(ws + 122816);
    unsigned short* csrc   = (unsigned short*)(ws + 122880);
    unsigned short* Gb     = (unsigned short*)(ws + 2201088); // aliases bh (dead after csr)
    float*          bufB   = (float*)(ws + 4761088);          // aliases ebuf (dead after csr)
    int*            bh     = (int*)(ws + 2201088);
    int*            ebuf   = (int*)(ws + 4761088);

    k_prep<<<G1, 256, 0, stream>>>(ei, bt, bh, ebuf, outacc, cntinv, done);
    k_csr <<<NB, 256, 0, stream>>>(ebuf, bh, coff, deg, dinv, csrc);

    k_gemm<<<(NN + TMR - 1) / TMR, 256, 0, stream>>>(x, W1, dinv, Gb, NN);
    k_gather<<<(NN + 3) / 4, 256, 0, stream>>>(Gb, coff, deg, csrc, dinv, b1, bufB);
    k_gemm<<<(NN + TMR - 1) / TMR, 256, 0, stream>>>(bufB, W2, dinv, Gb, NN);
    k_gatherpool<<<(NN + 3) / 4, 256, 0, stream>>>(Gb, coff, deg, csrc, dinv, b2,
                                                   bt, Wl, bl, cntinv, outacc, done,
                                                   (float*)d_out);
}

// Round 3
// 251.171 us; speedup vs baseline: 1.3235x; 1.1878x over previous
//
#include <hip/hip_runtime.h>

#define NN 10000     // nodes
#define NE 640000    // edges
#define NG 64        // graphs
#define NF 128       // feature dim (both layers)
#define NC 10        // classes
#define TMR 16       // gemm row tile
#define TKC 32       // gemm k chunk
#define NB 250       // dst buckets (40 nodes each)
#define BSZ 40       // nodes per bucket
#define G1 512       // blocks in prep pass (2 blocks/CU)
#define ECHUNK 1250  // edges per block (G1*ECHUNK == NE)
#define CAP 32       // ebuf slots per (bucket, block); mean 5, P(>32) ~ 5e-12
#define CCAP 4096    // csrc entries per bucket; mean 2560, +30 sigma

// ---------------- ws layout (bytes) ----------------
// 0        coff    (10000 int)            40000
// 40000    deg     (10000 int)            40000
// 80000    dinv    (10000 f32)            40000
// 120000   outacc  (64*10 f32)            2560   <- pooled@Wl accumulator
// 122560   cntinv  (64 f32)               256    <- 1/nodes-per-graph
// 122880   csrc    (250*4096 ushort)      2048000
// 2201088  bh      (250*512 int, 512KB) | Gb (10000*128 bf16, 2.56MB)  [bh dead after csr]
// 4761088  ebuf    (128000*32 int, 16.4MB) | bufB (10000*128 f32, 5.12MB) [ebuf dead after csr]
//
// Round-1 lesson: device-scope f32 atomics resolve past the XCD L2s at
// ~32B RMW each -> reduce to 10 floats/wave in registers first.
// Round-2 lesson: per-block __threadfence + hot done-counter = L2
// writeback/invalidate storm across 2500 blocks; the gather's L2-resident
// working set (164MB of Gb reads) kept getting flushed -> latency-bound at
// 60% occupancy, 0.9% HBM, 4.9% VALU. Fix: ZERO fences in hot kernels;
// the final 640-float reduction moves to a 1-block k_fin (stream-order
// release/acquire at kernel boundary provides visibility).

__device__ __forceinline__ unsigned short f2bf(float f) {   // RNE
    unsigned int u = __float_as_uint(f);
    return (unsigned short)((u + 0x7FFF + ((u >> 16) & 1)) >> 16);
}
__device__ __forceinline__ float bf_lo(unsigned int p) {
    return __uint_as_float(p << 16);
}
__device__ __forceinline__ float bf_hi(unsigned int p) {
    return __uint_as_float(p & 0xFFFF0000u);
}

// Wave-uniform detection of int64 vs int32 index buffers. For little-endian
// int64, every odd 32-bit word is the (always-zero here) high half.
__device__ __forceinline__ int detect64(const int* w, long span) {
    int lane = threadIdx.x & 63;
    long e = (long)lane * (span - 1) / 63;
    return (__ballot(w[2 * e + 1] != 0) == 0ULL) ? 1 : 0;
}

__device__ __forceinline__ int ld_idx(const void* p, long i, int is64) {
    return is64 ? (int)((const long long*)p)[i] : ((const int*)p)[i];
}

// Fused hist + scatter, single pass over the edge stream (dst/src cached in
// registers between the histogram and the scatter). Block 0 zeroes outacc;
// block 1 wave 0 computes cntinv[g] via 64 parallel binary searches on the
// sorted batch vector (overlapped with the other blocks' edge work).
__global__ __launch_bounds__(256) void k_prep(const void* __restrict__ ei,
                                              const void* __restrict__ batch,
                                              int* __restrict__ bh,
                                              int* __restrict__ ebuf,
                                              float* __restrict__ outacc,
                                              float* __restrict__ cntinv) {
    int is64 = detect64((const int*)ei, NE);
    __shared__ int hist[256];
    __shared__ int cur[256];
    int tid = threadIdx.x;
    hist[tid] = 0;
    __syncthreads();
    if (blockIdx.x == 0) {               // zero pool accumulator
        for (int i = tid; i < NG * NC; i += 256) outacc[i] = 0.f;
    }
    if (blockIdx.x == 1 && tid < NG) {   // cntinv via binary search (wave 0)
        int isb = detect64((const int*)batch, NN / 2);
        int lo0 = 0, hi0 = NN;
        while (lo0 < hi0) {
            int m = (lo0 + hi0) >> 1;
            if (ld_idx(batch, m, isb) < tid) lo0 = m + 1; else hi0 = m;
        }
        int lo1 = lo0, hi1 = NN;
        while (lo1 < hi1) {
            int m = (lo1 + hi1) >> 1;
            if (ld_idx(batch, m, isb) < tid + 1) lo1 = m + 1; else hi1 = m;
        }
        cntinv[tid] = 1.0f / fmaxf((float)(lo1 - lo0), 1.0f);
    }
    int e0 = blockIdx.x * ECHUNK;
    int dstv[5], srcv[5];
#pragma unroll
    for (int i = 0; i < 5; ++i) {
        int r = tid + i * 256;
        if (r < ECHUNK) {
            long e = (long)e0 + r;
            dstv[i] = ld_idx(ei, (long)NE + e, is64);
            srcv[i] = ld_idx(ei, e, is64);
            atomicAdd(&hist[dstv[i] / BSZ], 1);
        } else {
            dstv[i] = -1; srcv[i] = 0;
        }
    }
    __syncthreads();
    if (tid < NB) {
        bh[tid * G1 + blockIdx.x] = min(hist[tid], CAP);
        cur[tid] = (tid * G1 + blockIdx.x) * CAP;
    }
    __syncthreads();
#pragma unroll
    for (int i = 0; i < 5; ++i) {
        if (tid + i * 256 < ECHUNK) {
            int dst = dstv[i], src = srcv[i];
            int b = dst / BSZ;
            int p = atomicAdd(&cur[b], 1);
            int lim = (b * G1 + blockIdx.x) * CAP + CAP;
            if (p < lim) ebuf[p] = ((dst - b * BSZ) << 14) | src;
        }
    }
}

// One block per bucket: count the 40 dsts from the bucket's slot ranges,
// prefix-scan serially, emit coff/deg/dinv, scatter csrc into the bucket's
// fixed CCAP region. (unchanged)
__global__ __launch_bounds__(256) void k_csr(const int* __restrict__ ebuf,
                                             const int* __restrict__ bh,
                                             int* __restrict__ coff,
                                             int* __restrict__ deg,
                                             float* __restrict__ dinv,
                                             unsigned short* __restrict__ csrc) {
    __shared__ int scnt[G1];
    __shared__ int dcount[BSZ];
    __shared__ int dstart[BSZ];
    __shared__ int cur[BSZ];
    int b = blockIdx.x, tid = threadIdx.x;
    for (int i = tid; i < G1; i += 256) scnt[i] = bh[b * G1 + i];
    if (tid < BSZ) dcount[tid] = 0;
    __syncthreads();
    for (int blk = tid; blk < G1; blk += 256) {
        int c = scnt[blk];
        int base = (b * G1 + blk) * CAP;
        for (int i = 0; i < c; ++i)
            atomicAdd(&dcount[ebuf[base + i] >> 14], 1);
    }
    __syncthreads();
    if (tid == 0) {
        int run = 0;
        for (int i = 0; i < BSZ; ++i) {
            dstart[i] = run; cur[i] = b * CCAP + run; run += dcount[i];
        }
    }
    __syncthreads();
    if (tid < BSZ) {
        coff[b * BSZ + tid] = b * CCAP + dstart[tid];
        deg[b * BSZ + tid] = dcount[tid];
        dinv[b * BSZ + tid] = rsqrtf((float)dcount[tid] + 1.0f);
    }
    __syncthreads();
    for (int blk = tid; blk < G1; blk += 256) {
        int c = scnt[blk];
        int base = (b * G1 + blk) * CAP;
        for (int i = 0; i < c; ++i) {
            int pk = ebuf[base + i];
            int p = atomicAdd(&cur[pk >> 14], 1);
            csrc[p] = (unsigned short)(pk & 16383);
        }
    }
}

// Y(bf16) = (X @ W) * dinv[row]. 625 blocks x (16 rows x 128 cols), 256 thr;
// per-thread 2 rows x 4 cols. (unchanged — tuned in prior session)
__global__ __launch_bounds__(256) void k_gemm(const float* __restrict__ X,
                                              const float* __restrict__ W,
                                              const float* __restrict__ dinv,
                                              unsigned short* __restrict__ Y,
                                              int nrows) {
    __shared__ float sX[TKC * 20];       // [k][m] stride 20, 2.6 KB
    __shared__ float sW[32 * 132];       // 16.9 KB, 32 col-panels of 4
    int tid = threadIdx.x;
    int rg = tid & 7;                    // rows rg*2, rg*2+1
    int cg = tid >> 3;                   // cols cg*4 .. cg*4+3 (0..31)
    int m0 = blockIdx.x * TMR;
    float acc[2][4] = {{0.f}};
    for (int kc = 0; kc < NF / TKC; ++kc) {
        int k0 = kc * TKC;
        if (tid < 128) {                 // stage X^T (16 rows x 32 k)
            int row = tid >> 3, kq = tid & 7;
            int mm = m0 + row; if (mm > nrows - 1) mm = nrows - 1;
            float4 v = *(const float4*)(X + (size_t)mm * NF + k0 + kq * 4);
            sX[(kq * 4 + 0) * 20 + row] = v.x;
            sX[(kq * 4 + 1) * 20 + row] = v.y;
            sX[(kq * 4 + 2) * 20 + row] = v.z;
            sX[(kq * 4 + 3) * 20 + row] = v.w;
        }
#pragma unroll
        for (int j = 0; j < 4; ++j) {    // stage W panels (4 float4 per thread)
            int idx = tid + 256 * j;
            int k = idx >> 5, cq = idx & 31;
            float4 v = *(const float4*)(W + (size_t)(k0 + k) * NF + cq * 4);
            *(float4*)(sW + cq * 132 + k * 4) = v;
        }
        __syncthreads();
#pragma unroll 8
        for (int k = 0; k < TKC; ++k) {
            float2 xf = *(const float2*)(sX + k * 20 + rg * 2);
            float4 wf = *(const float4*)(sW + cg * 132 + k * 4);
            acc[0][0] = fmaf(xf.x, wf.x, acc[0][0]);
            acc[0][1] = fmaf(xf.x, wf.y, acc[0][1]);
            acc[0][2] = fmaf(xf.x, wf.z, acc[0][2]);
            acc[0][3] = fmaf(xf.x, wf.w, acc[0][3]);
            acc[1][0] = fmaf(xf.y, wf.x, acc[1][0]);
            acc[1][1] = fmaf(xf.y, wf.y, acc[1][1]);
            acc[1][2] = fmaf(xf.y, wf.z, acc[1][2]);
            acc[1][3] = fmaf(xf.y, wf.w, acc[1][3]);
        }
        __syncthreads();
    }
#pragma unroll
    for (int r = 0; r < 2; ++r) {
        int m = m0 + rg * 2 + r;
        if (m < nrows) {
            float ds = dinv[m];
            ushort4 h;
            h.x = f2bf(acc[r][0] * ds);
            h.y = f2bf(acc[r][1] * ds);
            h.z = f2bf(acc[r][2] * ds);
            h.w = f2bf(acc[r][3] * ds);
            *(ushort4*)(Y + (size_t)m * NF + cg * 4) = h;
        }
    }
}

// Shared accumulation core: one wave per node, quarter-wave (16 lanes x
// uint4 = full 256B row) per edge; 8-deep then 4-deep then single tail for
// deep MLP; fp32 accumulation. After the xor16/32 shuffles ALL 64 lanes
// hold the reduced sums.
__device__ __forceinline__ void gacc_node(const unsigned short* __restrict__ G,
                                          const unsigned short* __restrict__ csrc,
                                          int beg, int end, int q, int f,
                                          float a[8]) {
    int e = beg + q;
    for (; e + 28 < end; e += 32) {
        int s0 = csrc[e];      int s1 = csrc[e + 4];
        int s2 = csrc[e + 8];  int s3 = csrc[e + 12];
        int s4 = csrc[e + 16]; int s5 = csrc[e + 20];
        int s6 = csrc[e + 24]; int s7 = csrc[e + 28];
        uint4 p0 = ((const uint4*)(G + (size_t)s0 * NF))[f];
        uint4 p1 = ((const uint4*)(G + (size_t)s1 * NF))[f];
        uint4 p2 = ((const uint4*)(G + (size_t)s2 * NF))[f];
        uint4 p3 = ((const uint4*)(G + (size_t)s3 * NF))[f];
        uint4 p4 = ((const uint4*)(G + (size_t)s4 * NF))[f];
        uint4 p5 = ((const uint4*)(G + (size_t)s5 * NF))[f];
        uint4 p6 = ((const uint4*)(G + (size_t)s6 * NF))[f];
        uint4 p7 = ((const uint4*)(G + (size_t)s7 * NF))[f];
        a[0] += bf_lo(p0.x); a[1] += bf_hi(p0.x); a[2] += bf_lo(p0.y); a[3] += bf_hi(p0.y);
        a[4] += bf_lo(p0.z); a[5] += bf_hi(p0.z); a[6] += bf_lo(p0.w); a[7] += bf_hi(p0.w);
        a[0] += bf_lo(p1.x); a[1] += bf_hi(p1.x); a[2] += bf_lo(p1.y); a[3] += bf_hi(p1.y);
        a[4] += bf_lo(p1.z); a[5] += bf_hi(p1.z); a[6] += bf_lo(p1.w); a[7] += bf_hi(p1.w);
        a[0] += bf_lo(p2.x); a[1] += bf_hi(p2.x); a[2] += bf_lo(p2.y); a[3] += bf_hi(p2.y);
        a[4] += bf_lo(p2.z); a[5] += bf_hi(p2.z); a[6] += bf_lo(p2.w); a[7] += bf_hi(p2.w);
        a[0] += bf_lo(p3.x); a[1] += bf_hi(p3.x); a[2] += bf_lo(p3.y); a[3] += bf_hi(p3.y);
        a[4] += bf_lo(p3.z); a[5] += bf_hi(p3.z); a[6] += bf_lo(p3.w); a[7] += bf_hi(p3.w);
        a[0] += bf_lo(p4.x); a[1] += bf_hi(p4.x); a[2] += bf_lo(p4.y); a[3] += bf_hi(p4.y);
        a[4] += bf_lo(p4.z); a[5] += bf_hi(p4.z); a[6] += bf_lo(p4.w); a[7] += bf_hi(p4.w);
        a[0] += bf_lo(p5.x); a[1] += bf_hi(p5.x); a[2] += bf_lo(p5.y); a[3] += bf_hi(p5.y);
        a[4] += bf_lo(p5.z); a[5] += bf_hi(p5.z); a[6] += bf_lo(p5.w); a[7] += bf_hi(p5.w);
        a[0] += bf_lo(p6.x); a[1] += bf_hi(p6.x); a[2] += bf_lo(p6.y); a[3] += bf_hi(p6.y);
        a[4] += bf_lo(p6.z); a[5] += bf_hi(p6.z); a[6] += bf_lo(p6.w); a[7] += bf_hi(p6.w);
        a[0] += bf_lo(p7.x); a[1] += bf_hi(p7.x); a[2] += bf_lo(p7.y); a[3] += bf_hi(p7.y);
        a[4] += bf_lo(p7.z); a[5] += bf_hi(p7.z); a[6] += bf_lo(p7.w); a[7] += bf_hi(p7.w);
    }
    for (; e + 12 < end; e += 16) {
        int s0 = csrc[e];
        int s1 = csrc[e + 4];
        int s2 = csrc[e + 8];
        int s3 = csrc[e + 12];
        uint4 p0 = ((const uint4*)(G + (size_t)s0 * NF))[f];
        uint4 p1 = ((const uint4*)(G + (size_t)s1 * NF))[f];
        uint4 p2 = ((const uint4*)(G + (size_t)s2 * NF))[f];
        uint4 p3 = ((const uint4*)(G + (size_t)s3 * NF))[f];
        a[0] += bf_lo(p0.x); a[1] += bf_hi(p0.x); a[2] += bf_lo(p0.y); a[3] += bf_hi(p0.y);
        a[4] += bf_lo(p0.z); a[5] += bf_hi(p0.z); a[6] += bf_lo(p0.w); a[7] += bf_hi(p0.w);
        a[0] += bf_lo(p1.x); a[1] += bf_hi(p1.x); a[2] += bf_lo(p1.y); a[3] += bf_hi(p1.y);
        a[4] += bf_lo(p1.z); a[5] += bf_hi(p1.z); a[6] += bf_lo(p1.w); a[7] += bf_hi(p1.w);
        a[0] += bf_lo(p2.x); a[1] += bf_hi(p2.x); a[2] += bf_lo(p2.y); a[3] += bf_hi(p2.y);
        a[4] += bf_lo(p2.z); a[5] += bf_hi(p2.z); a[6] += bf_lo(p2.w); a[7] += bf_hi(p2.w);
        a[0] += bf_lo(p3.x); a[1] += bf_hi(p3.x); a[2] += bf_lo(p3.y); a[3] += bf_hi(p3.y);
        a[4] += bf_lo(p3.z); a[5] += bf_hi(p3.z); a[6] += bf_lo(p3.w); a[7] += bf_hi(p3.w);
    }
    for (; e < end; e += 4) {
        int s = csrc[e];
        uint4 p = ((const uint4*)(G + (size_t)s * NF))[f];
        a[0] += bf_lo(p.x); a[1] += bf_hi(p.x); a[2] += bf_lo(p.y); a[3] += bf_hi(p.y);
        a[4] += bf_lo(p.z); a[5] += bf_hi(p.z); a[6] += bf_lo(p.w); a[7] += bf_hi(p.w);
    }
#pragma unroll
    for (int j = 0; j < 8; ++j) a[j] += __shfl_xor(a[j], 16);
#pragma unroll
    for (int j = 0; j < 8; ++j) a[j] += __shfl_xor(a[j], 32);
}

// Layer-1 gather: OUT[n] = relu( dinv[n]*( sum_e G[csrc[e]] + G[n] ) + bias ).
__global__ __launch_bounds__(256) void k_gather(const unsigned short* __restrict__ G,
                                                const int* __restrict__ off,
                                                const int* __restrict__ dg,
                                                const unsigned short* __restrict__ csrc,
                                                const float* __restrict__ dinv,
                                                const float* __restrict__ bias,
                                                float* __restrict__ OUT) {
    int wid = threadIdx.x >> 6, lane = threadIdx.x & 63;
    int q = lane >> 4, f = lane & 15;
    int n = blockIdx.x * 4 + wid;
    if (n >= NN) return;
    int beg = off[n], end = beg + dg[n];
    float din = dinv[n];
    float a[8] = {0.f, 0.f, 0.f, 0.f, 0.f, 0.f, 0.f, 0.f};
    gacc_node(G, csrc, beg, end, q, f, a);
    if (q == 0) {
        uint4 sp = ((const uint4*)(G + (size_t)n * NF))[f];
        float4 b0 = ((const float4*)bias)[2 * f];
        float4 b1 = ((const float4*)bias)[2 * f + 1];
        float4 o0, o1;
        o0.x = fmaxf(fmaf(din, a[0] + bf_lo(sp.x), b0.x), 0.f);
        o0.y = fmaxf(fmaf(din, a[1] + bf_hi(sp.x), b0.y), 0.f);
        o0.z = fmaxf(fmaf(din, a[2] + bf_lo(sp.y), b0.z), 0.f);
        o0.w = fmaxf(fmaf(din, a[3] + bf_hi(sp.y), b0.w), 0.f);
        o1.x = fmaxf(fmaf(din, a[4] + bf_lo(sp.z), b1.x), 0.f);
        o1.y = fmaxf(fmaf(din, a[5] + bf_hi(sp.z), b1.y), 0.f);
        o1.z = fmaxf(fmaf(din, a[6] + bf_lo(sp.w), b1.z), 0.f);
        o1.w = fmaxf(fmaf(din, a[7] + bf_hi(sp.w), b1.w), 0.f);
        ((float4*)(OUT + (size_t)n * NF))[2 * f] = o0;
        ((float4*)(OUT + (size_t)n * NF))[2 * f + 1] = o1;
    }
}

// Layer-2 gather fused with mean-pool + final linear. Waves are FULLY
// independent (one __syncthreads for the Wl stage, then nothing): each wave
// computes its node's relu'd h (lane f holds features f*8..f*8+7 after the
// in-gacc xor-reduce), multiplies into the conflict-free [j][c][f] LDS copy
// of Wl, xor-reduces over f, pre-scales by cntinv[g], and lane 0 issues 10
// fire-and-forget device atomics (25K total). No fences, no done counter —
// k_fin (next launch) reads outacc under stream-order visibility.
__global__ __launch_bounds__(256) void k_gatherpool(const unsigned short* __restrict__ G,
                                                    const int* __restrict__ off,
                                                    const int* __restrict__ dg,
                                                    const unsigned short* __restrict__ csrc,
                                                    const float* __restrict__ dinv,
                                                    const float* __restrict__ bias,
                                                    const void* __restrict__ batch,
                                                    const float* __restrict__ Wl,
                                                    const float* __restrict__ cntinv,
                                                    float* __restrict__ outacc) {
    __shared__ float sWl2[8 * NC * 16];  // [j][c][f], 5 KB, conflict-free reads
    int tid = threadIdx.x;
    for (int i = tid; i < 8 * NC * 16; i += 256) {
        int j = i / (NC * 16);
        int r = i - j * (NC * 16);
        int c = r >> 4, f0 = r & 15;
        sWl2[i] = Wl[(f0 * 8 + j) * NC + c];
    }
    int isb64 = detect64((const int*)batch, NN / 2);
    int wid = tid >> 6, lane = tid & 63;
    int q = lane >> 4, f = lane & 15;
    int n = blockIdx.x * 4 + wid;        // grid is exactly NN/4 -> always valid
    int beg = off[n], end = beg + dg[n];
    float din = dinv[n];
    float a[8] = {0.f, 0.f, 0.f, 0.f, 0.f, 0.f, 0.f, 0.f};
    __syncthreads();                     // sWl2 ready; last block-wide sync
    gacc_node(G, csrc, beg, end, q, f, a);
    int g = ld_idx(batch, n, isb64);
    uint4 sp = ((const uint4*)(G + (size_t)n * NF))[f];
    float4 b0 = ((const float4*)bias)[2 * f];
    float4 b1 = ((const float4*)bias)[2 * f + 1];
    float h[8];
    h[0] = fmaxf(fmaf(din, a[0] + bf_lo(sp.x), b0.x), 0.f);
    h[1] = fmaxf(fmaf(din, a[1] + bf_hi(sp.x), b0.y), 0.f);
    h[2] = fmaxf(fmaf(din, a[2] + bf_lo(sp.y), b0.z), 0.f);
    h[3] = fmaxf(fmaf(din, a[3] + bf_hi(sp.y), b0.w), 0.f);
    h[4] = fmaxf(fmaf(din, a[4] + bf_lo(sp.z), b1.x), 0.f);
    h[5] = fmaxf(fmaf(din, a[5] + bf_hi(sp.z), b1.y), 0.f);
    h[6] = fmaxf(fmaf(din, a[6] + bf_lo(sp.w), b1.z), 0.f);
    h[7] = fmaxf(fmaf(din, a[7] + bf_hi(sp.w), b1.w), 0.f);
    float p[NC];
#pragma unroll
    for (int c = 0; c < NC; ++c) p[c] = 0.f;
#pragma unroll
    for (int j = 0; j < 8; ++j) {
        const float* wrow = sWl2 + j * (NC * 16) + f;  // [c*16 + f]
#pragma unroll
        for (int c = 0; c < NC; ++c) p[c] = fmaf(h[j], wrow[c * 16], p[c]);
    }
#pragma unroll
    for (int c = 0; c < NC; ++c) {       // reduce over f (bits 0..3)
        p[c] += __shfl_xor(p[c], 1);
        p[c] += __shfl_xor(p[c], 2);
        p[c] += __shfl_xor(p[c], 4);
        p[c] += __shfl_xor(p[c], 8);
    }
    if (lane == 0) {                     // 10 fire-and-forget atomics per wave
        float ci = cntinv[g];
        float* dst = outacc + g * NC;
#pragma unroll
        for (int c = 0; c < NC; ++c) atomicAdd(dst + c, p[c] * ci);
    }
}

// Tiny epilogue: out = outacc + bl. Stream order makes the prior kernel's
// device atomics visible.
__global__ __launch_bounds__(256) void k_fin(const float* __restrict__ outacc,
                                             const float* __restrict__ bl,
                                             float* __restrict__ out) {
    int tid = threadIdx.x;
    for (int i = tid; i < NG * NC; i += 256) {
        int g = i / NC, c = i - g * NC;
        out[i] = outacc[i] + bl[c];
        (void)g;
    }
}

extern "C" void kernel_launch(void* const* d_in, const int* in_sizes, int n_in,
                              void* d_out, int out_size, void* d_ws, size_t ws_size,
                              hipStream_t stream) {
    const float* x  = (const float*)d_in[0];
    const void*  ei = d_in[1];
    const void*  bt = d_in[2];
    const float* W1 = (const float*)d_in[3];
    const float* b1 = (const float*)d_in[4];
    const float* W2 = (const float*)d_in[5];
    const float* b2 = (const float*)d_in[6];
    const float* Wl = (const float*)d_in[7];
    const float* bl = (const float*)d_in[8];

    char* ws = (char*)d_ws;
    int*            coff   = (int*)(ws + 0);
    int*            deg    = (int*)(ws + 40000);
    float*          dinv   = (float*)(ws + 80000);
    float*          outacc = (float*)(ws + 120000);
    float*          cntinv = (float*)(ws + 122560);
    unsigned short* csrc   = (unsigned short*)(ws + 122880);
    unsigned short* Gb     = (unsigned short*)(ws + 2201088); // aliases bh (dead after csr)
    float*          bufB   = (float*)(ws + 4761088);          // aliases ebuf (dead after csr)
    int*            bh     = (int*)(ws + 2201088);
    int*            ebuf   = (int*)(ws + 4761088);

    k_prep<<<G1, 256, 0, stream>>>(ei, bt, bh, ebuf, outacc, cntinv);
    k_csr <<<NB, 256, 0, stream>>>(ebuf, bh, coff, deg, dinv, csrc);

    k_gemm<<<(NN + TMR - 1) / TMR, 256, 0, stream>>>(x, W1, dinv, Gb, NN);
    k_gather<<<(NN + 3) / 4, 256, 0, stream>>>(Gb, coff, deg, csrc, dinv, b1, bufB);
    k_gemm<<<(NN + TMR - 1) / TMR, 256, 0, stream>>>(bufB, W2, dinv, Gb, NN);
    k_gatherpool<<<(NN + 3) / 4, 256, 0, stream>>>(Gb, coff, deg, csrc, dinv, b2,
                                                   bt, Wl, cntinv, outacc);
    k_fin<<<1, 256, 0, stream>>>(outacc, bl, (float*)d_out);
}

// Round 5
// 249.968 us; speedup vs baseline: 1.3299x; 1.0048x over previous
//
#include <hip/hip_runtime.h>

#define NN 10000     // nodes
#define NE 640000    // edges
#define NG 64        // graphs
#define NF 128       // feature dim (both layers)
#define NC 10        // classes
#define TMR 16       // gemm row tile
#define TKC 32       // gemm k chunk
#define NB 250       // dst buckets (40 nodes each)
#define BSZ 40       // nodes per bucket
#define G1 512       // blocks in prep pass (2 blocks/CU)
#define ECHUNK 1250  // edges per block (G1*ECHUNK == NE)
#define CAP 32       // ebuf slots per (bucket, block); mean 5, P(>32) ~ 5e-12
#define CCAP 3072    // csrc entries per bucket; mean 2560 (sigma~51), +10 sigma

// ---------------- ws layout (bytes) ----------------
// 0        coff    (10000 int)            40000
// 40000    deg     (10000 int)            40000
// 80000    dinv    (10000 f32)            40000
// 120000   outacc  (64*10 f32)            2560   <- pooled@Wl accumulator
// 122560   cntinv  (64 f32)               256    <- 1/nodes-per-graph
// 122880   csrc    (250*3072 ushort)      1536000
// 2201088  bh      (250*512 int, 512KB) | Gb (10000*128 bf16, 2.56MB)  [bh dead after csr]
// 4761088  ebuf    (128000*32 int, 16.4MB) | bufB (10000*128 f32, 5.12MB) [ebuf dead after csr]
//
// Round-1 lesson: device-scope f32 atomics resolve past the XCD L2s at
// ~32B RMW each -> reduce to 10 floats/wave in registers first.
// Round-2 lesson: per-block __threadfence + hot done-counter = L2 flush
// storm -> zero fences in hot kernels; k_fin reads under stream order.
// Round-3 lesson: VGPR_Count=36 in the gather => compiler serialized the
// csrc->addr->G-row dependent chain (one ~600cy round trip per edge).
// Fix: preload the node's <=128 sources into ONE packed register per lane
// (coalesced 128B read), distribute via __shfl (no VMEM on the critical
// path), 8 independent uint4 row-loads in flight, launch_bounds(256,4).
// Round-4: container failed twice (infra, no GPU evidence) — resubmit.

__device__ __forceinline__ unsigned short f2bf(float f) {   // RNE
    unsigned int u = __float_as_uint(f);
    return (unsigned short)((u + 0x7FFF + ((u >> 16) & 1)) >> 16);
}
__device__ __forceinline__ float bf_lo(unsigned int p) {
    return __uint_as_float(p << 16);
}
__device__ __forceinline__ float bf_hi(unsigned int p) {
    return __uint_as_float(p & 0xFFFF0000u);
}

// Wave-uniform detection of int64 vs int32 index buffers. For little-endian
// int64, every odd 32-bit word is the (always-zero here) high half.
__device__ __forceinline__ int detect64(const int* w, long span) {
    int lane = threadIdx.x & 63;
    long e = (long)lane * (span - 1) / 63;
    return (__ballot(w[2 * e + 1] != 0) == 0ULL) ? 1 : 0;
}

__device__ __forceinline__ int ld_idx(const void* p, long i, int is64) {
    return is64 ? (int)((const long long*)p)[i] : ((const int*)p)[i];
}

// Fused hist + scatter, single pass over the edge stream (dst/src cached in
// registers between the histogram and the scatter). Block 0 zeroes outacc;
// block 1 wave 0 computes cntinv[g] via 64 parallel binary searches on the
// sorted batch vector (overlapped with the other blocks' edge work).
__global__ __launch_bounds__(256) void k_prep(const void* __restrict__ ei,
                                              const void* __restrict__ batch,
                                              int* __restrict__ bh,
                                              int* __restrict__ ebuf,
                                              float* __restrict__ outacc,
                                              float* __restrict__ cntinv) {
    int is64 = detect64((const int*)ei, NE);
    __shared__ int hist[256];
    __shared__ int cur[256];
    int tid = threadIdx.x;
    hist[tid] = 0;
    __syncthreads();
    if (blockIdx.x == 0) {               // zero pool accumulator
        for (int i = tid; i < NG * NC; i += 256) outacc[i] = 0.f;
    }
    if (blockIdx.x == 1 && tid < NG) {   // cntinv via binary search (wave 0)
        int isb = detect64((const int*)batch, NN / 2);
        int lo0 = 0, hi0 = NN;
        while (lo0 < hi0) {
            int m = (lo0 + hi0) >> 1;
            if (ld_idx(batch, m, isb) < tid) lo0 = m + 1; else hi0 = m;
        }
        int lo1 = lo0, hi1 = NN;
        while (lo1 < hi1) {
            int m = (lo1 + hi1) >> 1;
            if (ld_idx(batch, m, isb) < tid + 1) lo1 = m + 1; else hi1 = m;
        }
        cntinv[tid] = 1.0f / fmaxf((float)(lo1 - lo0), 1.0f);
    }
    int e0 = blockIdx.x * ECHUNK;
    int dstv[5], srcv[5];
#pragma unroll
    for (int i = 0; i < 5; ++i) {
        int r = tid + i * 256;
        if (r < ECHUNK) {
            long e = (long)e0 + r;
            dstv[i] = ld_idx(ei, (long)NE + e, is64);
            srcv[i] = ld_idx(ei, e, is64);
            atomicAdd(&hist[dstv[i] / BSZ], 1);
        } else {
            dstv[i] = -1; srcv[i] = 0;
        }
    }
    __syncthreads();
    if (tid < NB) {
        bh[tid * G1 + blockIdx.x] = min(hist[tid], CAP);
        cur[tid] = (tid * G1 + blockIdx.x) * CAP;
    }
    __syncthreads();
#pragma unroll
    for (int i = 0; i < 5; ++i) {
        if (tid + i * 256 < ECHUNK) {
            int dst = dstv[i], src = srcv[i];
            int b = dst / BSZ;
            int p = atomicAdd(&cur[b], 1);
            int lim = (b * G1 + blockIdx.x) * CAP + CAP;
            if (p < lim) ebuf[p] = ((dst - b * BSZ) << 14) | src;
        }
    }
}

// One block per bucket: count the 40 dsts from the bucket's slot ranges,
// prefix-scan serially, emit coff/deg/dinv, scatter csrc into the bucket's
// fixed CCAP region. (unchanged)
__global__ __launch_bounds__(256) void k_csr(const int* __restrict__ ebuf,
                                             const int* __restrict__ bh,
                                             int* __restrict__ coff,
                                             int* __restrict__ deg,
                                             float* __restrict__ dinv,
                                             unsigned short* __restrict__ csrc) {
    __shared__ int scnt[G1];
    __shared__ int dcount[BSZ];
    __shared__ int dstart[BSZ];
    __shared__ int cur[BSZ];
    int b = blockIdx.x, tid = threadIdx.x;
    for (int i = tid; i < G1; i += 256) scnt[i] = bh[b * G1 + i];
    if (tid < BSZ) dcount[tid] = 0;
    __syncthreads();
    for (int blk = tid; blk < G1; blk += 256) {
        int c = scnt[blk];
        int base = (b * G1 + blk) * CAP;
        for (int i = 0; i < c; ++i)
            atomicAdd(&dcount[ebuf[base + i] >> 14], 1);
    }
    __syncthreads();
    if (tid == 0) {
        int run = 0;
        for (int i = 0; i < BSZ; ++i) {
            dstart[i] = run; cur[i] = b * CCAP + run; run += dcount[i];
        }
    }
    __syncthreads();
    if (tid < BSZ) {
        coff[b * BSZ + tid] = b * CCAP + dstart[tid];
        deg[b * BSZ + tid] = dcount[tid];
        dinv[b * BSZ + tid] = rsqrtf((float)dcount[tid] + 1.0f);
    }
    __syncthreads();
    for (int blk = tid; blk < G1; blk += 256) {
        int c = scnt[blk];
        int base = (b * G1 + blk) * CAP;
        for (int i = 0; i < c; ++i) {
            int pk = ebuf[base + i];
            int p = atomicAdd(&cur[pk >> 14], 1);
            csrc[p] = (unsigned short)(pk & 16383);
        }
    }
}

// Y(bf16) = (X @ W) * dinv[row]. 625 blocks x (16 rows x 128 cols), 256 thr;
// per-thread 2 rows x 4 cols. (unchanged — tuned in prior session)
__global__ __launch_bounds__(256) void k_gemm(const float* __restrict__ X,
                                              const float* __restrict__ W,
                                              const float* __restrict__ dinv,
                                              unsigned short* __restrict__ Y,
                                              int nrows) {
    __shared__ float sX[TKC * 20];       // [k][m] stride 20, 2.6 KB
    __shared__ float sW[32 * 132];       // 16.9 KB, 32 col-panels of 4
    int tid = threadIdx.x;
    int rg = tid & 7;                    // rows rg*2, rg*2+1
    int cg = tid >> 3;                   // cols cg*4 .. cg*4+3 (0..31)
    int m0 = blockIdx.x * TMR;
    float acc[2][4] = {{0.f}};
    for (int kc = 0; kc < NF / TKC; ++kc) {
        int k0 = kc * TKC;
        if (tid < 128) {                 // stage X^T (16 rows x 32 k)
            int row = tid >> 3, kq = tid & 7;
            int mm = m0 + row; if (mm > nrows - 1) mm = nrows - 1;
            float4 v = *(const float4*)(X + (size_t)mm * NF + k0 + kq * 4);
            sX[(kq * 4 + 0) * 20 + row] = v.x;
            sX[(kq * 4 + 1) * 20 + row] = v.y;
            sX[(kq * 4 + 2) * 20 + row] = v.z;
            sX[(kq * 4 + 3) * 20 + row] = v.w;
        }
#pragma unroll
        for (int j = 0; j < 4; ++j) {    // stage W panels (4 float4 per thread)
            int idx = tid + 256 * j;
            int k = idx >> 5, cq = idx & 31;
            float4 v = *(const float4*)(W + (size_t)(k0 + k) * NF + cq * 4);
            *(float4*)(sW + cq * 132 + k * 4) = v;
        }
        __syncthreads();
#pragma unroll 8
        for (int k = 0; k < TKC; ++k) {
            float2 xf = *(const float2*)(sX + k * 20 + rg * 2);
            float4 wf = *(const float4*)(sW + cg * 132 + k * 4);
            acc[0][0] = fmaf(xf.x, wf.x, acc[0][0]);
            acc[0][1] = fmaf(xf.x, wf.y, acc[0][1]);
            acc[0][2] = fmaf(xf.x, wf.z, acc[0][2]);
            acc[0][3] = fmaf(xf.x, wf.w, acc[0][3]);
            acc[1][0] = fmaf(xf.y, wf.x, acc[1][0]);
            acc[1][1] = fmaf(xf.y, wf.y, acc[1][1]);
            acc[1][2] = fmaf(xf.y, wf.z, acc[1][2]);
            acc[1][3] = fmaf(xf.y, wf.w, acc[1][3]);
        }
        __syncthreads();
    }
#pragma unroll
    for (int r = 0; r < 2; ++r) {
        int m = m0 + rg * 2 + r;
        if (m < nrows) {
            float ds = dinv[m];
            ushort4 h;
            h.x = f2bf(acc[r][0] * ds);
            h.y = f2bf(acc[r][1] * ds);
            h.z = f2bf(acc[r][2] * ds);
            h.w = f2bf(acc[r][3] * ds);
            *(ushort4*)(Y + (size_t)m * NF + cg * 4) = h;
        }
    }
}

// Gather core, register-preloaded indices. One wave per node; quarter-wave
// (16 lanes x uint4 = full 256B row) per edge. Lane l packs csrc[beg+l]
// (lo16) and csrc[beg+64+l] (hi16) into sv; edge sources come from __shfl
// of sv (LDS pipe, ~60cy) instead of a dependent global load. The 8-deep
// body keeps 8 independent uint4 row loads in flight. Loop trip counts are
// wave-uniform (nfull%32==0 etc.); the last partial group predicates only
// the accumulate. deg>128 falls back to direct csrc loads (P ~ 1e-15).
// After the xor16/32 shuffles ALL 64 lanes hold the reduced sums.
__device__ __forceinline__ void gacc_node(const unsigned short* __restrict__ G,
                                          const unsigned short* __restrict__ csrc,
                                          int beg, int end, int q, int f, int lane,
                                          float a[8]) {
    int dg = end - beg;
    int nreg = min(dg, 128);
    unsigned int sv = 0;
    if (lane < dg) sv = csrc[beg + lane];
    if (64 + lane < dg) sv |= ((unsigned int)csrc[beg + 64 + lane]) << 16;
    int vi = q;
    int nfull = nreg & ~31;
    for (; vi < nfull; vi += 32) {       // 8 edges per quarter per iter
        int s[8];
#pragma unroll
        for (int j = 0; j < 8; ++j) {
            int e = vi + 4 * j;
            unsigned int w = (unsigned int)__shfl((int)sv, e & 63, 64);
            s[j] = (int)((w >> ((e >> 6) << 4)) & 0xFFFFu);
        }
        uint4 p[8];
#pragma unroll
        for (int j = 0; j < 8; ++j)
            p[j] = ((const uint4*)(G + (size_t)s[j] * NF))[f];
#pragma unroll
        for (int j = 0; j < 8; ++j) {
            a[0] += bf_lo(p[j].x); a[1] += bf_hi(p[j].x);
            a[2] += bf_lo(p[j].y); a[3] += bf_hi(p[j].y);
            a[4] += bf_lo(p[j].z); a[5] += bf_hi(p[j].z);
            a[6] += bf_lo(p[j].w); a[7] += bf_hi(p[j].w);
        }
    }
    int nfull16 = nreg & ~15;
    for (; vi < nfull16; vi += 16) {     // one 4-deep group
        int s[4];
#pragma unroll
        for (int j = 0; j < 4; ++j) {
            int e = vi + 4 * j;
            unsigned int w = (unsigned int)__shfl((int)sv, e & 63, 64);
            s[j] = (int)((w >> ((e >> 6) << 4)) & 0xFFFFu);
        }
        uint4 p[4];
#pragma unroll
        for (int j = 0; j < 4; ++j)
            p[j] = ((const uint4*)(G + (size_t)s[j] * NF))[f];
#pragma unroll
        for (int j = 0; j < 4; ++j) {
            a[0] += bf_lo(p[j].x); a[1] += bf_hi(p[j].x);
            a[2] += bf_lo(p[j].y); a[3] += bf_hi(p[j].y);
            a[4] += bf_lo(p[j].z); a[5] += bf_hi(p[j].z);
            a[6] += bf_lo(p[j].w); a[7] += bf_hi(p[j].w);
        }
    }
    int npad = (nreg + 3) & ~3;
    for (; vi < npad; vi += 4) {         // predicated tail, uniform trips
        int e = min(vi, nreg - 1);
        unsigned int w = (unsigned int)__shfl((int)sv, e & 63, 64);
        int s = (int)((w >> ((e >> 6) << 4)) & 0xFFFFu);
        uint4 p = ((const uint4*)(G + (size_t)s * NF))[f];
        if (vi < nreg) {
            a[0] += bf_lo(p.x); a[1] += bf_hi(p.x);
            a[2] += bf_lo(p.y); a[3] += bf_hi(p.y);
            a[4] += bf_lo(p.z); a[5] += bf_hi(p.z);
            a[6] += bf_lo(p.w); a[7] += bf_hi(p.w);
        }
    }
    for (int e2 = beg + 128 + q; e2 < end; e2 += 4) {  // deg>128 fallback
        int s = csrc[e2];
        uint4 p = ((const uint4*)(G + (size_t)s * NF))[f];
        a[0] += bf_lo(p.x); a[1] += bf_hi(p.x);
        a[2] += bf_lo(p.y); a[3] += bf_hi(p.y);
        a[4] += bf_lo(p.z); a[5] += bf_hi(p.z);
        a[6] += bf_lo(p.w); a[7] += bf_hi(p.w);
    }
#pragma unroll
    for (int j = 0; j < 8; ++j) a[j] += __shfl_xor(a[j], 16);
#pragma unroll
    for (int j = 0; j < 8; ++j) a[j] += __shfl_xor(a[j], 32);
}

// Layer-1 gather: OUT[n] = relu( dinv[n]*( sum_e G[csrc[e]] + G[n] ) + bias ).
__global__ __launch_bounds__(256, 4) void k_gather(const unsigned short* __restrict__ G,
                                                   const int* __restrict__ off,
                                                   const int* __restrict__ dg,
                                                   const unsigned short* __restrict__ csrc,
                                                   const float* __restrict__ dinv,
                                                   const float* __restrict__ bias,
                                                   float* __restrict__ OUT) {
    int wid = threadIdx.x >> 6, lane = threadIdx.x & 63;
    int q = lane >> 4, f = lane & 15;
    int n = blockIdx.x * 4 + wid;
    if (n >= NN) return;
    int beg = off[n], end = beg + dg[n];
    float din = dinv[n];
    float a[8] = {0.f, 0.f, 0.f, 0.f, 0.f, 0.f, 0.f, 0.f};
    gacc_node(G, csrc, beg, end, q, f, lane, a);
    if (q == 0) {
        uint4 sp = ((const uint4*)(G + (size_t)n * NF))[f];
        float4 b0 = ((const float4*)bias)[2 * f];
        float4 b1 = ((const float4*)bias)[2 * f + 1];
        float4 o0, o1;
        o0.x = fmaxf(fmaf(din, a[0] + bf_lo(sp.x), b0.x), 0.f);
        o0.y = fmaxf(fmaf(din, a[1] + bf_hi(sp.x), b0.y), 0.f);
        o0.z = fmaxf(fmaf(din, a[2] + bf_lo(sp.y), b0.z), 0.f);
        o0.w = fmaxf(fmaf(din, a[3] + bf_hi(sp.y), b0.w), 0.f);
        o1.x = fmaxf(fmaf(din, a[4] + bf_lo(sp.z), b1.x), 0.f);
        o1.y = fmaxf(fmaf(din, a[5] + bf_hi(sp.z), b1.y), 0.f);
        o1.z = fmaxf(fmaf(din, a[6] + bf_lo(sp.w), b1.z), 0.f);
        o1.w = fmaxf(fmaf(din, a[7] + bf_hi(sp.w), b1.w), 0.f);
        ((float4*)(OUT + (size_t)n * NF))[2 * f] = o0;
        ((float4*)(OUT + (size_t)n * NF))[2 * f + 1] = o1;
    }
}

// Layer-2 gather fused with mean-pool + final linear. Waves fully
// independent after the one sWl2 staging sync: relu'd h (lane f holds
// features f*8..f*8+7) multiplies into the conflict-free [j][c][f] LDS
// copy of Wl, xor-reduces over f, pre-scales by cntinv[g], lane 0 issues
// 10 fire-and-forget device atomics. No fences; k_fin reads outacc under
// stream-order visibility.
__global__ __launch_bounds__(256, 4) void k_gatherpool(const unsigned short* __restrict__ G,
                                                       const int* __restrict__ off,
                                                       const int* __restrict__ dg,
                                                       const unsigned short* __restrict__ csrc,
                                                       const float* __restrict__ dinv,
                                                       const float* __restrict__ bias,
                                                       const void* __restrict__ batch,
                                                       const float* __restrict__ Wl,
                                                       const float* __restrict__ cntinv,
                                                       float* __restrict__ outacc) {
    __shared__ float sWl2[8 * NC * 16];  // [j][c][f], 5 KB, conflict-free reads
    int tid = threadIdx.x;
    for (int i = tid; i < 8 * NC * 16; i += 256) {
        int j = i / (NC * 16);
        int r = i - j * (NC * 16);
        int c = r >> 4, f0 = r & 15;
        sWl2[i] = Wl[(f0 * 8 + j) * NC + c];
    }
    int isb64 = detect64((const int*)batch, NN / 2);
    int wid = tid >> 6, lane = tid & 63;
    int q = lane >> 4, f = lane & 15;
    int n = blockIdx.x * 4 + wid;        // grid is exactly NN/4 -> always valid
    int beg = off[n], end = beg + dg[n];
    float din = dinv[n];
    float a[8] = {0.f, 0.f, 0.f, 0.f, 0.f, 0.f, 0.f, 0.f};
    __syncthreads();                     // sWl2 ready; last block-wide sync
    gacc_node(G, csrc, beg, end, q, f, lane, a);
    int g = ld_idx(batch, n, isb64);
    uint4 sp = ((const uint4*)(G + (size_t)n * NF))[f];
    float4 b0 = ((const float4*)bias)[2 * f];
    float4 b1 = ((const float4*)bias)[2 * f + 1];
    float h[8];
    h[0] = fmaxf(fmaf(din, a[0] + bf_lo(sp.x), b0.x), 0.f);
    h[1] = fmaxf(fmaf(din, a[1] + bf_hi(sp.x), b0.y), 0.f);
    h[2] = fmaxf(fmaf(din, a[2] + bf_lo(sp.y), b0.z), 0.f);
    h[3] = fmaxf(fmaf(din, a[3] + bf_hi(sp.y), b0.w), 0.f);
    h[4] = fmaxf(fmaf(din, a[4] + bf_lo(sp.z), b1.x), 0.f);
    h[5] = fmaxf(fmaf(din, a[5] + bf_hi(sp.z), b1.y), 0.f);
    h[6] = fmaxf(fmaf(din, a[6] + bf_lo(sp.w), b1.z), 0.f);
    h[7] = fmaxf(fmaf(din, a[7] + bf_hi(sp.w), b1.w), 0.f);
    float p[NC];
#pragma unroll
    for (int c = 0; c < NC; ++c) p[c] = 0.f;
#pragma unroll
    for (int j = 0; j < 8; ++j) {
        const float* wrow = sWl2 + j * (NC * 16) + f;  // [c*16 + f]
#pragma unroll
        for (int c = 0; c < NC; ++c) p[c] = fmaf(h[j], wrow[c * 16], p[c]);
    }
#pragma unroll
    for (int c = 0; c < NC; ++c) {       // reduce over f (bits 0..3)
        p[c] += __shfl_xor(p[c], 1);
        p[c] += __shfl_xor(p[c], 2);
        p[c] += __shfl_xor(p[c], 4);
        p[c] += __shfl_xor(p[c], 8);
    }
    if (lane == 0) {                     // 10 fire-and-forget atomics per wave
        float ci = cntinv[g];
        float* dst = outacc + g * NC;
#pragma unroll
        for (int c = 0; c < NC; ++c) atomicAdd(dst + c, p[c] * ci);
    }
}

// Tiny epilogue: out = outacc + bl. Stream order makes the prior kernel's
// device atomics visible.
__global__ __launch_bounds__(256) void k_fin(const float* __restrict__ outacc,
                                             const float* __restrict__ bl,
                                             float* __restrict__ out) {
    int tid = threadIdx.x;
    for (int i = tid; i < NG * NC; i += 256) {
        int c = i % NC;
        out[i] = outacc[i] + bl[c];
    }
}

extern "C" void kernel_launch(void* const* d_in, const int* in_sizes, int n_in,
                              void* d_out, int out_size, void* d_ws, size_t ws_size,
                              hipStream_t stream) {
    const float* x  = (const float*)d_in[0];
    const void*  ei = d_in[1];
    const void*  bt = d_in[2];
    const float* W1 = (const float*)d_in[3];
    const float* b1 = (const float*)d_in[4];
    const float* W2 = (const float*)d_in[5];
    const float* b2 = (const float*)d_in[6];
    const float* Wl = (const float*)d_in[7];
    const float* bl = (const float*)d_in[8];

    char* ws = (char*)d_ws;
    int*            coff   = (int*)(ws + 0);
    int*            deg    = (int*)(ws + 40000);
    float*          dinv   = (float*)(ws + 80000);
    float*          outacc = (float*)(ws + 120000);
    float*          cntinv = (float*)(ws + 122560);
    unsigned short* csrc   = (unsigned short*)(ws + 122880);
    unsigned short* Gb     = (unsigned short*)(ws + 2201088); // aliases bh (dead after csr)
    float*          bufB   = (float*)(ws + 4761088);          // aliases ebuf (dead after csr)
    int*            bh     = (int*)(ws + 2201088);
    int*            ebuf   = (int*)(ws + 4761088);

    k_prep<<<G1, 256, 0, stream>>>(ei, bt, bh, ebuf, outacc, cntinv);
    k_csr <<<NB, 256, 0, stream>>>(ebuf, bh, coff, deg, dinv, csrc);

    k_gemm<<<(NN + TMR - 1) / TMR, 256, 0, stream>>>(x, W1, dinv, Gb, NN);
    k_gather<<<(NN + 3) / 4, 256, 0, stream>>>(Gb, coff, deg, csrc, dinv, b1, bufB);
    k_gemm<<<(NN + TMR - 1) / TMR, 256, 0, stream>>>(bufB, W2, dinv, Gb, NN);
    k_gatherpool<<<(NN + 3) / 4, 256, 0, stream>>>(Gb, coff, deg, csrc, dinv, b2,
                                                   bt, Wl, cntinv, outacc);
    k_fin<<<1, 256, 0, stream>>>(outacc, bl, (float*)d_out);
}

// Round 6
// 171.857 us; speedup vs baseline: 1.9343x; 1.4545x over previous
//
#include <hip/hip_runtime.h>

#define NN 10000     // nodes
#define NE 640000    // edges
#define NG 64        // graphs
#define NF 128       // feature dim (both layers)
#define NC 10        // classes
#define TMR 16       // gemm row tile
#define TKC 32       // gemm k chunk
#define NB 250       // dst buckets (40 nodes each)
#define BSZ 40       // nodes per bucket
#define G1 512       // blocks in prep pass (2 blocks/CU)
#define ECHUNK 1250  // edges per block (G1*ECHUNK == NE)
#define CAP 32       // ebuf slots per (bucket, block); mean 5, P(>32) ~ 5e-12
#define CCAP 3072    // csrc entries per bucket; mean 2560 (sigma~51), +10 sigma
#define NSL 64       // outacc slices (atomic-contention spreading)

// ---------------- ws layout (bytes) ----------------
// 0        coff    (10000 int)            40000
// 40000    deg     (10000 int)            40000
// 80000    dinv    (10000 f32)            40000
// 120000   outacc  (64 slices x 640 f32)  163840 <- sliced pooled@Wl accumulator
// 283840   cntinv  (64 f32)               256
// 284160   csrc    (250*3072 ushort)      1536000
// 2201088  bh      (250*512 int, 512KB) | Gb (10000*128 bf16, 2.56MB)  [bh dead after csr]
// 4761088  ebuf    (128000*32 int, 16.4MB) | bufB (10000*128 f32, 5.12MB) [ebuf dead after csr]
//
// Round-1 lesson: device-scope f32 atomics resolve past the XCD L2s at
// ~32B RMW each -> reduce to 10 floats/wave in registers first.
// Round-2 lesson: per-block __threadfence + hot done-counter = L2 flush
// storm -> zero fences in hot kernels; k_fin reads under stream order.
// Round-3/5 lesson: the gather core was NEVER the gatherpool bottleneck —
// k_gather (same core, no atomics) runs ~40us while k_gatherpool sat at
// 110-120us. 100K atomicAdds onto 640 floats (~80 cachelines) serialize at
// the coherence point: ~156 waves x 10 RMWs per graph-line x ~80ns ~= 120us.
// Fix: 64 accumulator slices (blockIdx&63) -> per-line contention /64;
// k_fin sums the slices.

__device__ __forceinline__ unsigned short f2bf(float f) {   // RNE
    unsigned int u = __float_as_uint(f);
    return (unsigned short)((u + 0x7FFF + ((u >> 16) & 1)) >> 16);
}
__device__ __forceinline__ float bf_lo(unsigned int p) {
    return __uint_as_float(p << 16);
}
__device__ __forceinline__ float bf_hi(unsigned int p) {
    return __uint_as_float(p & 0xFFFF0000u);
}

// Wave-uniform detection of int64 vs int32 index buffers. For little-endian
// int64, every odd 32-bit word is the (always-zero here) high half.
__device__ __forceinline__ int detect64(const int* w, long span) {
    int lane = threadIdx.x & 63;
    long e = (long)lane * (span - 1) / 63;
    return (__ballot(w[2 * e + 1] != 0) == 0ULL) ? 1 : 0;
}

__device__ __forceinline__ int ld_idx(const void* p, long i, int is64) {
    return is64 ? (int)((const long long*)p)[i] : ((const int*)p)[i];
}

// Fused hist + scatter, single pass over the edge stream (dst/src cached in
// registers between the histogram and the scatter). Blocks 0..7 zero the
// sliced outacc (8 slices each); block 8 wave 0 computes cntinv[g] via 64
// parallel binary searches on the sorted batch vector (all overlapped with
// the other blocks' edge work).
__global__ __launch_bounds__(256) void k_prep(const void* __restrict__ ei,
                                              const void* __restrict__ batch,
                                              int* __restrict__ bh,
                                              int* __restrict__ ebuf,
                                              float* __restrict__ outacc,
                                              float* __restrict__ cntinv) {
    int is64 = detect64((const int*)ei, NE);
    __shared__ int hist[256];
    __shared__ int cur[256];
    int tid = threadIdx.x;
    hist[tid] = 0;
    __syncthreads();
    if (blockIdx.x < 8) {                // zero 8 slices each (160KB total)
        float* base = outacc + (size_t)blockIdx.x * 8 * NG * NC;
        for (int i = tid; i < 8 * NG * NC; i += 256) base[i] = 0.f;
    }
    if (blockIdx.x == 8 && tid < NG) {   // cntinv via binary search (wave 0)
        int isb = detect64((const int*)batch, NN / 2);
        int lo0 = 0, hi0 = NN;
        while (lo0 < hi0) {
            int m = (lo0 + hi0) >> 1;
            if (ld_idx(batch, m, isb) < tid) lo0 = m + 1; else hi0 = m;
        }
        int lo1 = lo0, hi1 = NN;
        while (lo1 < hi1) {
            int m = (lo1 + hi1) >> 1;
            if (ld_idx(batch, m, isb) < tid + 1) lo1 = m + 1; else hi1 = m;
        }
        cntinv[tid] = 1.0f / fmaxf((float)(lo1 - lo0), 1.0f);
    }
    int e0 = blockIdx.x * ECHUNK;
    int dstv[5], srcv[5];
#pragma unroll
    for (int i = 0; i < 5; ++i) {
        int r = tid + i * 256;
        if (r < ECHUNK) {
            long e = (long)e0 + r;
            dstv[i] = ld_idx(ei, (long)NE + e, is64);
            srcv[i] = ld_idx(ei, e, is64);
            atomicAdd(&hist[dstv[i] / BSZ], 1);
        } else {
            dstv[i] = -1; srcv[i] = 0;
        }
    }
    __syncthreads();
    if (tid < NB) {
        bh[tid * G1 + blockIdx.x] = min(hist[tid], CAP);
        cur[tid] = (tid * G1 + blockIdx.x) * CAP;
    }
    __syncthreads();
#pragma unroll
    for (int i = 0; i < 5; ++i) {
        if (tid + i * 256 < ECHUNK) {
            int dst = dstv[i], src = srcv[i];
            int b = dst / BSZ;
            int p = atomicAdd(&cur[b], 1);
            int lim = (b * G1 + blockIdx.x) * CAP + CAP;
            if (p < lim) ebuf[p] = ((dst - b * BSZ) << 14) | src;
        }
    }
}

// One block per bucket: count the 40 dsts from the bucket's slot ranges,
// prefix-scan serially, emit coff/deg/dinv, scatter csrc into the bucket's
// fixed CCAP region. (unchanged)
__global__ __launch_bounds__(256) void k_csr(const int* __restrict__ ebuf,
                                             const int* __restrict__ bh,
                                             int* __restrict__ coff,
                                             int* __restrict__ deg,
                                             float* __restrict__ dinv,
                                             unsigned short* __restrict__ csrc) {
    __shared__ int scnt[G1];
    __shared__ int dcount[BSZ];
    __shared__ int dstart[BSZ];
    __shared__ int cur[BSZ];
    int b = blockIdx.x, tid = threadIdx.x;
    for (int i = tid; i < G1; i += 256) scnt[i] = bh[b * G1 + i];
    if (tid < BSZ) dcount[tid] = 0;
    __syncthreads();
    for (int blk = tid; blk < G1; blk += 256) {
        int c = scnt[blk];
        int base = (b * G1 + blk) * CAP;
        for (int i = 0; i < c; ++i)
            atomicAdd(&dcount[ebuf[base + i] >> 14], 1);
    }
    __syncthreads();
    if (tid == 0) {
        int run = 0;
        for (int i = 0; i < BSZ; ++i) {
            dstart[i] = run; cur[i] = b * CCAP + run; run += dcount[i];
        }
    }
    __syncthreads();
    if (tid < BSZ) {
        coff[b * BSZ + tid] = b * CCAP + dstart[tid];
        deg[b * BSZ + tid] = dcount[tid];
        dinv[b * BSZ + tid] = rsqrtf((float)dcount[tid] + 1.0f);
    }
    __syncthreads();
    for (int blk = tid; blk < G1; blk += 256) {
        int c = scnt[blk];
        int base = (b * G1 + blk) * CAP;
        for (int i = 0; i < c; ++i) {
            int pk = ebuf[base + i];
            int p = atomicAdd(&cur[pk >> 14], 1);
            csrc[p] = (unsigned short)(pk & 16383);
        }
    }
}

// Y(bf16) = (X @ W) * dinv[row]. 625 blocks x (16 rows x 128 cols), 256 thr;
// per-thread 2 rows x 4 cols. (unchanged — tuned in prior session)
__global__ __launch_bounds__(256) void k_gemm(const float* __restrict__ X,
                                              const float* __restrict__ W,
                                              const float* __restrict__ dinv,
                                              unsigned short* __restrict__ Y,
                                              int nrows) {
    __shared__ float sX[TKC * 20];       // [k][m] stride 20, 2.6 KB
    __shared__ float sW[32 * 132];       // 16.9 KB, 32 col-panels of 4
    int tid = threadIdx.x;
    int rg = tid & 7;                    // rows rg*2, rg*2+1
    int cg = tid >> 3;                   // cols cg*4 .. cg*4+3 (0..31)
    int m0 = blockIdx.x * TMR;
    float acc[2][4] = {{0.f}};
    for (int kc = 0; kc < NF / TKC; ++kc) {
        int k0 = kc * TKC;
        if (tid < 128) {                 // stage X^T (16 rows x 32 k)
            int row = tid >> 3, kq = tid & 7;
            int mm = m0 + row; if (mm > nrows - 1) mm = nrows - 1;
            float4 v = *(const float4*)(X + (size_t)mm * NF + k0 + kq * 4);
            sX[(kq * 4 + 0) * 20 + row] = v.x;
            sX[(kq * 4 + 1) * 20 + row] = v.y;
            sX[(kq * 4 + 2) * 20 + row] = v.z;
            sX[(kq * 4 + 3) * 20 + row] = v.w;
        }
#pragma unroll
        for (int j = 0; j < 4; ++j) {    // stage W panels (4 float4 per thread)
            int idx = tid + 256 * j;
            int k = idx >> 5, cq = idx & 31;
            float4 v = *(const float4*)(W + (size_t)(k0 + k) * NF + cq * 4);
            *(float4*)(sW + cq * 132 + k * 4) = v;
        }
        __syncthreads();
#pragma unroll 8
        for (int k = 0; k < TKC; ++k) {
            float2 xf = *(const float2*)(sX + k * 20 + rg * 2);
            float4 wf = *(const float4*)(sW + cg * 132 + k * 4);
            acc[0][0] = fmaf(xf.x, wf.x, acc[0][0]);
            acc[0][1] = fmaf(xf.x, wf.y, acc[0][1]);
            acc[0][2] = fmaf(xf.x, wf.z, acc[0][2]);
            acc[0][3] = fmaf(xf.x, wf.w, acc[0][3]);
            acc[1][0] = fmaf(xf.y, wf.x, acc[1][0]);
            acc[1][1] = fmaf(xf.y, wf.y, acc[1][1]);
            acc[1][2] = fmaf(xf.y, wf.z, acc[1][2]);
            acc[1][3] = fmaf(xf.y, wf.w, acc[1][3]);
        }
        __syncthreads();
    }
#pragma unroll
    for (int r = 0; r < 2; ++r) {
        int m = m0 + rg * 2 + r;
        if (m < nrows) {
            float ds = dinv[m];
            ushort4 h;
            h.x = f2bf(acc[r][0] * ds);
            h.y = f2bf(acc[r][1] * ds);
            h.z = f2bf(acc[r][2] * ds);
            h.w = f2bf(acc[r][3] * ds);
            *(ushort4*)(Y + (size_t)m * NF + cg * 4) = h;
        }
    }
}

// Gather core, register-preloaded indices (unchanged from round 5, which
// passed and matches the direct-load variant's speed on k_gather).
__device__ __forceinline__ void gacc_node(const unsigned short* __restrict__ G,
                                          const unsigned short* __restrict__ csrc,
                                          int beg, int end, int q, int f, int lane,
                                          float a[8]) {
    int dg = end - beg;
    int nreg = min(dg, 128);
    unsigned int sv = 0;
    if (lane < dg) sv = csrc[beg + lane];
    if (64 + lane < dg) sv |= ((unsigned int)csrc[beg + 64 + lane]) << 16;
    int vi = q;
    int nfull = nreg & ~31;
    for (; vi < nfull; vi += 32) {       // 8 edges per quarter per iter
        int s[8];
#pragma unroll
        for (int j = 0; j < 8; ++j) {
            int e = vi + 4 * j;
            unsigned int w = (unsigned int)__shfl((int)sv, e & 63, 64);
            s[j] = (int)((w >> ((e >> 6) << 4)) & 0xFFFFu);
        }
        uint4 p[8];
#pragma unroll
        for (int j = 0; j < 8; ++j)
            p[j] = ((const uint4*)(G + (size_t)s[j] * NF))[f];
#pragma unroll
        for (int j = 0; j < 8; ++j) {
            a[0] += bf_lo(p[j].x); a[1] += bf_hi(p[j].x);
            a[2] += bf_lo(p[j].y); a[3] += bf_hi(p[j].y);
            a[4] += bf_lo(p[j].z); a[5] += bf_hi(p[j].z);
            a[6] += bf_lo(p[j].w); a[7] += bf_hi(p[j].w);
        }
    }
    int nfull16 = nreg & ~15;
    for (; vi < nfull16; vi += 16) {     // one 4-deep group
        int s[4];
#pragma unroll
        for (int j = 0; j < 4; ++j) {
            int e = vi + 4 * j;
            unsigned int w = (unsigned int)__shfl((int)sv, e & 63, 64);
            s[j] = (int)((w >> ((e >> 6) << 4)) & 0xFFFFu);
        }
        uint4 p[4];
#pragma unroll
        for (int j = 0; j < 4; ++j)
            p[j] = ((const uint4*)(G + (size_t)s[j] * NF))[f];
#pragma unroll
        for (int j = 0; j < 4; ++j) {
            a[0] += bf_lo(p[j].x); a[1] += bf_hi(p[j].x);
            a[2] += bf_lo(p[j].y); a[3] += bf_hi(p[j].y);
            a[4] += bf_lo(p[j].z); a[5] += bf_hi(p[j].z);
            a[6] += bf_lo(p[j].w); a[7] += bf_hi(p[j].w);
        }
    }
    int npad = (nreg + 3) & ~3;
    for (; vi < npad; vi += 4) {         // predicated tail, uniform trips
        int e = min(vi, nreg - 1);
        unsigned int w = (unsigned int)__shfl((int)sv, e & 63, 64);
        int s = (int)((w >> ((e >> 6) << 4)) & 0xFFFFu);
        uint4 p = ((const uint4*)(G + (size_t)s * NF))[f];
        if (vi < nreg) {
            a[0] += bf_lo(p.x); a[1] += bf_hi(p.x);
            a[2] += bf_lo(p.y); a[3] += bf_hi(p.y);
            a[4] += bf_lo(p.z); a[5] += bf_hi(p.z);
            a[6] += bf_lo(p.w); a[7] += bf_hi(p.w);
        }
    }
    for (int e2 = beg + 128 + q; e2 < end; e2 += 4) {  // deg>128 fallback
        int s = csrc[e2];
        uint4 p = ((const uint4*)(G + (size_t)s * NF))[f];
        a[0] += bf_lo(p.x); a[1] += bf_hi(p.x);
        a[2] += bf_lo(p.y); a[3] += bf_hi(p.y);
        a[4] += bf_lo(p.z); a[5] += bf_hi(p.z);
        a[6] += bf_lo(p.w); a[7] += bf_hi(p.w);
    }
#pragma unroll
    for (int j = 0; j < 8; ++j) a[j] += __shfl_xor(a[j], 16);
#pragma unroll
    for (int j = 0; j < 8; ++j) a[j] += __shfl_xor(a[j], 32);
}

// Layer-1 gather: OUT[n] = relu( dinv[n]*( sum_e G[csrc[e]] + G[n] ) + bias ).
__global__ __launch_bounds__(256, 4) void k_gather(const unsigned short* __restrict__ G,
                                                   const int* __restrict__ off,
                                                   const int* __restrict__ dg,
                                                   const unsigned short* __restrict__ csrc,
                                                   const float* __restrict__ dinv,
                                                   const float* __restrict__ bias,
                                                   float* __restrict__ OUT) {
    int wid = threadIdx.x >> 6, lane = threadIdx.x & 63;
    int q = lane >> 4, f = lane & 15;
    int n = blockIdx.x * 4 + wid;
    if (n >= NN) return;
    int beg = off[n], end = beg + dg[n];
    float din = dinv[n];
    float a[8] = {0.f, 0.f, 0.f, 0.f, 0.f, 0.f, 0.f, 0.f};
    gacc_node(G, csrc, beg, end, q, f, lane, a);
    if (q == 0) {
        uint4 sp = ((const uint4*)(G + (size_t)n * NF))[f];
        float4 b0 = ((const float4*)bias)[2 * f];
        float4 b1 = ((const float4*)bias)[2 * f + 1];
        float4 o0, o1;
        o0.x = fmaxf(fmaf(din, a[0] + bf_lo(sp.x), b0.x), 0.f);
        o0.y = fmaxf(fmaf(din, a[1] + bf_hi(sp.x), b0.y), 0.f);
        o0.z = fmaxf(fmaf(din, a[2] + bf_lo(sp.y), b0.z), 0.f);
        o0.w = fmaxf(fmaf(din, a[3] + bf_hi(sp.y), b0.w), 0.f);
        o1.x = fmaxf(fmaf(din, a[4] + bf_lo(sp.z), b1.x), 0.f);
        o1.y = fmaxf(fmaf(din, a[5] + bf_hi(sp.z), b1.y), 0.f);
        o1.z = fmaxf(fmaf(din, a[6] + bf_lo(sp.w), b1.z), 0.f);
        o1.w = fmaxf(fmaf(din, a[7] + bf_hi(sp.w), b1.w), 0.f);
        ((float4*)(OUT + (size_t)n * NF))[2 * f] = o0;
        ((float4*)(OUT + (size_t)n * NF))[2 * f + 1] = o1;
    }
}

// Layer-2 gather fused with mean-pool + final linear. Waves fully
// independent; after the in-register h@Wl + xor-reduce, lane 0 issues 10
// fire-and-forget atomics into the block's outacc SLICE (blockIdx&63) —
// per-cacheline contention drops 64x vs a single accumulator. No fences;
// k_fin sums slices under stream-order visibility.
__global__ __launch_bounds__(256, 4) void k_gatherpool(const unsigned short* __restrict__ G,
                                                       const int* __restrict__ off,
                                                       const int* __restrict__ dg,
                                                       const unsigned short* __restrict__ csrc,
                                                       const float* __restrict__ dinv,
                                                       const float* __restrict__ bias,
                                                       const void* __restrict__ batch,
                                                       const float* __restrict__ Wl,
                                                       const float* __restrict__ cntinv,
                                                       float* __restrict__ outacc) {
    __shared__ float sWl2[8 * NC * 16];  // [j][c][f], 5 KB, conflict-free reads
    int tid = threadIdx.x;
    for (int i = tid; i < 8 * NC * 16; i += 256) {
        int j = i / (NC * 16);
        int r = i - j * (NC * 16);
        int c = r >> 4, f0 = r & 15;
        sWl2[i] = Wl[(f0 * 8 + j) * NC + c];
    }
    int isb64 = detect64((const int*)batch, NN / 2);
    int wid = tid >> 6, lane = tid & 63;
    int q = lane >> 4, f = lane & 15;
    int n = blockIdx.x * 4 + wid;        // grid is exactly NN/4 -> always valid
    int beg = off[n], end = beg + dg[n];
    float din = dinv[n];
    float a[8] = {0.f, 0.f, 0.f, 0.f, 0.f, 0.f, 0.f, 0.f};
    __syncthreads();                     // sWl2 ready; last block-wide sync
    gacc_node(G, csrc, beg, end, q, f, lane, a);
    int g = ld_idx(batch, n, isb64);
    uint4 sp = ((const uint4*)(G + (size_t)n * NF))[f];
    float4 b0 = ((const float4*)bias)[2 * f];
    float4 b1 = ((const float4*)bias)[2 * f + 1];
    float h[8];
    h[0] = fmaxf(fmaf(din, a[0] + bf_lo(sp.x), b0.x), 0.f);
    h[1] = fmaxf(fmaf(din, a[1] + bf_hi(sp.x), b0.y), 0.f);
    h[2] = fmaxf(fmaf(din, a[2] + bf_lo(sp.y), b0.z), 0.f);
    h[3] = fmaxf(fmaf(din, a[3] + bf_hi(sp.y), b0.w), 0.f);
    h[4] = fmaxf(fmaf(din, a[4] + bf_lo(sp.z), b1.x), 0.f);
    h[5] = fmaxf(fmaf(din, a[5] + bf_hi(sp.z), b1.y), 0.f);
    h[6] = fmaxf(fmaf(din, a[6] + bf_lo(sp.w), b1.z), 0.f);
    h[7] = fmaxf(fmaf(din, a[7] + bf_hi(sp.w), b1.w), 0.f);
    float p[NC];
#pragma unroll
    for (int c = 0; c < NC; ++c) p[c] = 0.f;
#pragma unroll
    for (int j = 0; j < 8; ++j) {
        const float* wrow = sWl2 + j * (NC * 16) + f;  // [c*16 + f]
#pragma unroll
        for (int c = 0; c < NC; ++c) p[c] = fmaf(h[j], wrow[c * 16], p[c]);
    }
#pragma unroll
    for (int c = 0; c < NC; ++c) {       // reduce over f (bits 0..3)
        p[c] += __shfl_xor(p[c], 1);
        p[c] += __shfl_xor(p[c], 2);
        p[c] += __shfl_xor(p[c], 4);
        p[c] += __shfl_xor(p[c], 8);
    }
    if (lane == 0) {                     // 10 atomics into this block's slice
        float ci = cntinv[g];
        float* dst = outacc + (size_t)(blockIdx.x & (NSL - 1)) * NG * NC + g * NC;
#pragma unroll
        for (int c = 0; c < NC; ++c) atomicAdd(dst + c, p[c] * ci);
    }
}

// Epilogue: out = sum_slices(outacc) + bl. Stream order makes the prior
// kernel's device atomics visible.
__global__ __launch_bounds__(256) void k_fin(const float* __restrict__ outacc,
                                             const float* __restrict__ bl,
                                             float* __restrict__ out) {
    int tid = threadIdx.x;
    for (int i = tid; i < NG * NC; i += 256) {
        float s = 0.f;
#pragma unroll 8
        for (int sl = 0; sl < NSL; ++sl) s += outacc[(size_t)sl * NG * NC + i];
        out[i] = s + bl[i % NC];
    }
}

extern "C" void kernel_launch(void* const* d_in, const int* in_sizes, int n_in,
                              void* d_out, int out_size, void* d_ws, size_t ws_size,
                              hipStream_t stream) {
    const float* x  = (const float*)d_in[0];
    const void*  ei = d_in[1];
    const void*  bt = d_in[2];
    const float* W1 = (const float*)d_in[3];
    const float* b1 = (const float*)d_in[4];
    const float* W2 = (const float*)d_in[5];
    const float* b2 = (const float*)d_in[6];
    const float* Wl = (const float*)d_in[7];
    const float* bl = (const float*)d_in[8];

    char* ws = (char*)d_ws;
    int*            coff   = (int*)(ws + 0);
    int*            deg    = (int*)(ws + 40000);
    float*          dinv   = (float*)(ws + 80000);
    float*          outacc = (float*)(ws + 120000);   // 64 slices x 640 f32
    float*          cntinv = (float*)(ws + 283840);
    unsigned short* csrc   = (unsigned short*)(ws + 284160);
    unsigned short* Gb     = (unsigned short*)(ws + 2201088); // aliases bh (dead after csr)
    float*          bufB   = (float*)(ws + 4761088);          // aliases ebuf (dead after csr)
    int*            bh     = (int*)(ws + 2201088);
    int*            ebuf   = (int*)(ws + 4761088);

    k_prep<<<G1, 256, 0, stream>>>(ei, bt, bh, ebuf, outacc, cntinv);
    k_csr <<<NB, 256, 0, stream>>>(ebuf, bh, coff, deg, dinv, csrc);

    k_gemm<<<(NN + TMR - 1) / TMR, 256, 0, stream>>>(x, W1, dinv, Gb, NN);
    k_gather<<<(NN + 3) / 4, 256, 0, stream>>>(Gb, coff, deg, csrc, dinv, b1, bufB);
    k_gemm<<<(NN + TMR - 1) / TMR, 256, 0, stream>>>(bufB, W2, dinv, Gb, NN);
    k_gatherpool<<<(NN + 3) / 4, 256, 0, stream>>>(Gb, coff, deg, csrc, dinv, b2,
                                                   bt, Wl, cntinv, outacc);
    k_fin<<<1, 256, 0, stream>>>(outacc, bl, (float*)d_out);
}

// Round 7
// 165.938 us; speedup vs baseline: 2.0033x; 1.0357x over previous
//
#include <hip/hip_runtime.h>

#define NN 10000     // nodes
#define NE 640000    // edges
#define NG 64        // graphs
#define NF 128       // feature dim (both layers)
#define NC 10        // classes
#define TMR 16       // gemm row tile
#define TKC 32       // gemm k chunk
#define NB 250       // dst buckets (40 nodes each)
#define BSZ 40       // nodes per bucket
#define G1 512       // blocks in prep pass (2 blocks/CU)
#define ECHUNK 1250  // edges per block (G1*ECHUNK == NE)
#define CAP 32       // ebuf slots per (bucket, block); mean 5, P(>32) ~ 5e-12
#define CCAP 3072    // csrc entries per bucket; mean 2560 (sigma~51), +10 sigma
#define NSL 64       // outacc slices (atomic-contention spreading)
#define MAXD 192     // per-wave LDS csrc staging capacity (deg mean 64, +16 sigma)

// ---------------- ws layout (bytes) ----------------
// 0        coff    (10000 int)            40000
// 40000    deg     (10000 int)            40000
// 80000    dinv    (10000 f32)            40000
// 120000   outacc  (64 slices x 640 f32)  163840
// 283840   cntinv  (64 f32)               256
// 284160   csrc    (250*3072 ushort)      1536000
// 2201088  bh      (250*512 int, 512KB) | Gb (10000*128 bf16, 2.56MB)  [bh dead after csr]
// 4761088  ebuf    (128000*32 int, 16.4MB) | bufB (10000*128 f32, 5.12MB) [ebuf dead after csr]
//
// Round-1: device atomics = ~32B RMW past XCD L2 -> reduce in registers 1st.
// Round-2: per-block fences+done-counter = L2 flush storm -> zero fences.
// Round-3/5: gatherpool was atomic-bound, NOT gather-core-bound.
// Round-6: slicing outacc (64x) fixed contention -> all kernels < 42us.
// Round-7: remove the index-delivery serializer in the gather core: stage
// each node's csrc list in LDS (wave-internal, no barrier) so the inner
// loop is ds_read_u16 -> addr -> 8 independent row loads (no bpermute, no
// dependent global index load). k_csr: single global pass, LDS-resident,
// wave-parallel scans.

__device__ __forceinline__ unsigned short f2bf(float f) {   // RNE
    unsigned int u = __float_as_uint(f);
    return (unsigned short)((u + 0x7FFF + ((u >> 16) & 1)) >> 16);
}
__device__ __forceinline__ float bf_lo(unsigned int p) {
    return __uint_as_float(p << 16);
}
__device__ __forceinline__ float bf_hi(unsigned int p) {
    return __uint_as_float(p & 0xFFFF0000u);
}

// Wave-uniform detection of int64 vs int32 index buffers.
__device__ __forceinline__ int detect64(const int* w, long span) {
    int lane = threadIdx.x & 63;
    long e = (long)lane * (span - 1) / 63;
    return (__ballot(w[2 * e + 1] != 0) == 0ULL) ? 1 : 0;
}

__device__ __forceinline__ int ld_idx(const void* p, long i, int is64) {
    return is64 ? (int)((const long long*)p)[i] : ((const int*)p)[i];
}

// Fused hist + scatter, single pass over the edge stream. Blocks 0..7 zero
// the sliced outacc; block 8 wave 0 computes cntinv[g] via binary search.
__global__ __launch_bounds__(256) void k_prep(const void* __restrict__ ei,
                                              const void* __restrict__ batch,
                                              int* __restrict__ bh,
                                              int* __restrict__ ebuf,
                                              float* __restrict__ outacc,
                                              float* __restrict__ cntinv) {
    int is64 = detect64((const int*)ei, NE);
    __shared__ int hist[256];
    __shared__ int cur[256];
    int tid = threadIdx.x;
    hist[tid] = 0;
    __syncthreads();
    if (blockIdx.x < 8) {
        float* base = outacc + (size_t)blockIdx.x * 8 * NG * NC;
        for (int i = tid; i < 8 * NG * NC; i += 256) base[i] = 0.f;
    }
    if (blockIdx.x == 8 && tid < NG) {
        int isb = detect64((const int*)batch, NN / 2);
        int lo0 = 0, hi0 = NN;
        while (lo0 < hi0) {
            int m = (lo0 + hi0) >> 1;
            if (ld_idx(batch, m, isb) < tid) lo0 = m + 1; else hi0 = m;
        }
        int lo1 = lo0, hi1 = NN;
        while (lo1 < hi1) {
            int m = (lo1 + hi1) >> 1;
            if (ld_idx(batch, m, isb) < tid + 1) lo1 = m + 1; else hi1 = m;
        }
        cntinv[tid] = 1.0f / fmaxf((float)(lo1 - lo0), 1.0f);
    }
    int e0 = blockIdx.x * ECHUNK;
    int dstv[5], srcv[5];
#pragma unroll
    for (int i = 0; i < 5; ++i) {
        int r = tid + i * 256;
        if (r < ECHUNK) {
            long e = (long)e0 + r;
            dstv[i] = ld_idx(ei, (long)NE + e, is64);
            srcv[i] = ld_idx(ei, e, is64);
            atomicAdd(&hist[dstv[i] / BSZ], 1);
        } else {
            dstv[i] = -1; srcv[i] = 0;
        }
    }
    __syncthreads();
    if (tid < NB) {
        bh[tid * G1 + blockIdx.x] = min(hist[tid], CAP);
        cur[tid] = (tid * G1 + blockIdx.x) * CAP;
    }
    __syncthreads();
#pragma unroll
    for (int i = 0; i < 5; ++i) {
        if (tid + i * 256 < ECHUNK) {
            int dst = dstv[i], src = srcv[i];
            int b = dst / BSZ;
            int p = atomicAdd(&cur[b], 1);
            int lim = (b * G1 + blockIdx.x) * CAP + CAP;
            if (p < lim) ebuf[p] = ((dst - b * BSZ) << 14) | src;
        }
    }
}

// One block per bucket, single global pass: (1) load the 512 cell counts,
// (2) 512-wide exclusive scan (shfl + cross-wave combine), (3) copy cell
// entries into LDS-resident eb[] (ONE global read of ebuf), (4) count dsts
// via LDS atomics, (5) wave-parallel 40-scan -> coff/deg/dinv, (6) scatter
// csrc from LDS.
__global__ __launch_bounds__(256) void k_csr(const int* __restrict__ ebuf,
                                             const int* __restrict__ bh,
                                             int* __restrict__ coff,
                                             int* __restrict__ deg,
                                             float* __restrict__ dinv,
                                             unsigned short* __restrict__ csrc) {
    __shared__ int scnt[G1];
    __shared__ int cbase[G1];
    __shared__ int wsum[4];
    __shared__ int eb[CCAP];             // 12 KB: the bucket's packed edges
    __shared__ int dcount[BSZ];
    __shared__ int cur[BSZ];
    int b = blockIdx.x, tid = threadIdx.x;
    int lane = tid & 63, wv = tid >> 6;
    for (int i = tid; i < G1; i += 256) scnt[i] = bh[b * G1 + i];
    if (tid < BSZ) dcount[tid] = 0;
    __syncthreads();
    int v0 = scnt[2 * tid], v1 = scnt[2 * tid + 1];
    int lsum = v0 + v1;
    int pref = lsum;
    for (int o = 1; o < 64; o <<= 1) {
        int t = __shfl_up(pref, o, 64);
        if (lane >= o) pref += t;
    }
    if (lane == 63) wsum[wv] = pref;
    __syncthreads();
    int off = 0;
#pragma unroll
    for (int j = 0; j < 4; ++j) if (j < wv) off += wsum[j];
    int ex = pref - lsum + off;
    cbase[2 * tid] = ex;
    cbase[2 * tid + 1] = ex + v0;
    int tot = wsum[0] + wsum[1] + wsum[2] + wsum[3];
    if (tot > CCAP) tot = CCAP;
    __syncthreads();
#pragma unroll
    for (int cp = 0; cp < 2; ++cp) {     // copy cells 2t, 2t+1 into LDS
        int cell = 2 * tid + cp;
        int c = scnt[cell], lb = cbase[cell];
        int gb = (b * G1 + cell) * CAP;
        if (lb + c > CCAP) c = max(0, CCAP - lb);
        for (int i = 0; i < c; ++i) eb[lb + i] = ebuf[gb + i];
    }
    __syncthreads();
    for (int i = tid; i < tot; i += 256)
        atomicAdd(&dcount[eb[i] >> 14], 1);
    __syncthreads();
    if (tid < 64) {                      // wave 0: 40-element exclusive scan
        int d = (tid < BSZ) ? dcount[tid] : 0;
        int pr = d;
        for (int o = 1; o < 64; o <<= 1) {
            int t = __shfl_up(pr, o, 64);
            if (tid >= o) pr += t;
        }
        if (tid < BSZ) {
            int st = pr - d;
            cur[tid] = b * CCAP + st;
            coff[b * BSZ + tid] = b * CCAP + st;
            deg[b * BSZ + tid] = d;
            dinv[b * BSZ + tid] = rsqrtf((float)d + 1.0f);
        }
    }
    __syncthreads();
    for (int i = tid; i < tot; i += 256) {
        int pk = eb[i];
        int p = atomicAdd(&cur[pk >> 14], 1);
        csrc[p] = (unsigned short)(pk & 16383);
    }
}

// Y(bf16) = (X @ W) * dinv[row]. (unchanged — tuned in prior session)
__global__ __launch_bounds__(256) void k_gemm(const float* __restrict__ X,
                                              const float* __restrict__ W,
                                              const float* __restrict__ dinv,
                                              unsigned short* __restrict__ Y,
                                              int nrows) {
    __shared__ float sX[TKC * 20];       // [k][m] stride 20, 2.6 KB
    __shared__ float sW[32 * 132];       // 16.9 KB, 32 col-panels of 4
    int tid = threadIdx.x;
    int rg = tid & 7;                    // rows rg*2, rg*2+1
    int cg = tid >> 3;                   // cols cg*4 .. cg*4+3 (0..31)
    int m0 = blockIdx.x * TMR;
    float acc[2][4] = {{0.f}};
    for (int kc = 0; kc < NF / TKC; ++kc) {
        int k0 = kc * TKC;
        if (tid < 128) {                 // stage X^T (16 rows x 32 k)
            int row = tid >> 3, kq = tid & 7;
            int mm = m0 + row; if (mm > nrows - 1) mm = nrows - 1;
            float4 v = *(const float4*)(X + (size_t)mm * NF + k0 + kq * 4);
            sX[(kq * 4 + 0) * 20 + row] = v.x;
            sX[(kq * 4 + 1) * 20 + row] = v.y;
            sX[(kq * 4 + 2) * 20 + row] = v.z;
            sX[(kq * 4 + 3) * 20 + row] = v.w;
        }
#pragma unroll
        for (int j = 0; j < 4; ++j) {    // stage W panels
            int idx = tid + 256 * j;
            int k = idx >> 5, cq = idx & 31;
            float4 v = *(const float4*)(W + (size_t)(k0 + k) * NF + cq * 4);
            *(float4*)(sW + cq * 132 + k * 4) = v;
        }
        __syncthreads();
#pragma unroll 8
        for (int k = 0; k < TKC; ++k) {
            float2 xf = *(const float2*)(sX + k * 20 + rg * 2);
            float4 wf = *(const float4*)(sW + cg * 132 + k * 4);
            acc[0][0] = fmaf(xf.x, wf.x, acc[0][0]);
            acc[0][1] = fmaf(xf.x, wf.y, acc[0][1]);
            acc[0][2] = fmaf(xf.x, wf.z, acc[0][2]);
            acc[0][3] = fmaf(xf.x, wf.w, acc[0][3]);
            acc[1][0] = fmaf(xf.y, wf.x, acc[1][0]);
            acc[1][1] = fmaf(xf.y, wf.y, acc[1][1]);
            acc[1][2] = fmaf(xf.y, wf.z, acc[1][2]);
            acc[1][3] = fmaf(xf.y, wf.w, acc[1][3]);
        }
        __syncthreads();
    }
#pragma unroll
    for (int r = 0; r < 2; ++r) {
        int m = m0 + rg * 2 + r;
        if (m < nrows) {
            float ds = dinv[m];
            ushort4 h;
            h.x = f2bf(acc[r][0] * ds);
            h.y = f2bf(acc[r][1] * ds);
            h.z = f2bf(acc[r][2] * ds);
            h.w = f2bf(acc[r][3] * ds);
            *(ushort4*)(Y + (size_t)m * NF + cg * 4) = h;
        }
    }
}

// Gather core, LDS-staged indices. One wave per node; quarter-wave (16
// lanes x uint4 = full 256B row) per edge. The node's csrc list is staged
// into this wave's LDS region first (coalesced, wave-internal — no
// barrier); the inner loop is then ds_read_u16 -> addr -> row load with 8
// independent row loads per group (no bpermute, no dependent global index
// load on the critical path). deg>MAXD tail falls back to direct loads.
// After the xor16/32 shuffles ALL 64 lanes hold the reduced sums.
__device__ __forceinline__ void gacc_node(const unsigned short* __restrict__ G,
                                          const unsigned short* __restrict__ csrc,
                                          unsigned short* ls,
                                          int beg, int end, int q, int f, int lane,
                                          float a[8]) {
    int dg = end - beg;
    int nst = min(dg, MAXD);
    for (int i = lane; i < nst; i += 64) ls[i] = csrc[beg + i];
    int vi = q;
    int nfull = nst & ~31;
    for (; vi < nfull; vi += 32) {       // 8 edges per quarter per iter
        int s[8];
#pragma unroll
        for (int j = 0; j < 8; ++j) s[j] = ls[vi + 4 * j];
        uint4 p[8];
#pragma unroll
        for (int j = 0; j < 8; ++j)
            p[j] = ((const uint4*)(G + (size_t)s[j] * NF))[f];
#pragma unroll
        for (int j = 0; j < 8; ++j) {
            a[0] += bf_lo(p[j].x); a[1] += bf_hi(p[j].x);
            a[2] += bf_lo(p[j].y); a[3] += bf_hi(p[j].y);
            a[4] += bf_lo(p[j].z); a[5] += bf_hi(p[j].z);
            a[6] += bf_lo(p[j].w); a[7] += bf_hi(p[j].w);
        }
    }
    int nfull16 = nst & ~15;
    for (; vi < nfull16; vi += 16) {     // one 4-deep group
        int s[4];
#pragma unroll
        for (int j = 0; j < 4; ++j) s[j] = ls[vi + 4 * j];
        uint4 p[4];
#pragma unroll
        for (int j = 0; j < 4; ++j)
            p[j] = ((const uint4*)(G + (size_t)s[j] * NF))[f];
#pragma unroll
        for (int j = 0; j < 4; ++j) {
            a[0] += bf_lo(p[j].x); a[1] += bf_hi(p[j].x);
            a[2] += bf_lo(p[j].y); a[3] += bf_hi(p[j].y);
            a[4] += bf_lo(p[j].z); a[5] += bf_hi(p[j].z);
            a[6] += bf_lo(p[j].w); a[7] += bf_hi(p[j].w);
        }
    }
    int npad = (nst + 3) & ~3;
    for (; vi < npad; vi += 4) {         // predicated tail, uniform trips
        int s = ls[min(vi, nst - 1)];
        uint4 p = ((const uint4*)(G + (size_t)s * NF))[f];
        if (vi < nst) {
            a[0] += bf_lo(p.x); a[1] += bf_hi(p.x);
            a[2] += bf_lo(p.y); a[3] += bf_hi(p.y);
            a[4] += bf_lo(p.z); a[5] += bf_hi(p.z);
            a[6] += bf_lo(p.w); a[7] += bf_hi(p.w);
        }
    }
    for (int e2 = beg + MAXD + q; e2 < end; e2 += 4) {  // deg>MAXD fallback
        int s = csrc[e2];
        uint4 p = ((const uint4*)(G + (size_t)s * NF))[f];
        a[0] += bf_lo(p.x); a[1] += bf_hi(p.x);
        a[2] += bf_lo(p.y); a[3] += bf_hi(p.y);
        a[4] += bf_lo(p.z); a[5] += bf_hi(p.z);
        a[6] += bf_lo(p.w); a[7] += bf_hi(p.w);
    }
#pragma unroll
    for (int j = 0; j < 8; ++j) a[j] += __shfl_xor(a[j], 16);
#pragma unroll
    for (int j = 0; j < 8; ++j) a[j] += __shfl_xor(a[j], 32);
}

// Layer-1 gather: OUT[n] = relu( dinv[n]*( sum_e G[csrc[e]] + G[n] ) + bias ).
__global__ __launch_bounds__(256, 4) void k_gather(const unsigned short* __restrict__ G,
                                                   const int* __restrict__ off,
                                                   const int* __restrict__ dg,
                                                   const unsigned short* __restrict__ csrc,
                                                   const float* __restrict__ dinv,
                                                   const float* __restrict__ bias,
                                                   float* __restrict__ OUT) {
    __shared__ unsigned short lsbuf[4][MAXD];
    int wid = threadIdx.x >> 6, lane = threadIdx.x & 63;
    int q = lane >> 4, f = lane & 15;
    int n = blockIdx.x * 4 + wid;
    if (n >= NN) return;
    int beg = off[n], end = beg + dg[n];
    float din = dinv[n];
    float a[8] = {0.f, 0.f, 0.f, 0.f, 0.f, 0.f, 0.f, 0.f};
    gacc_node(G, csrc, lsbuf[wid], beg, end, q, f, lane, a);
    if (q == 0) {
        uint4 sp = ((const uint4*)(G + (size_t)n * NF))[f];
        float4 b0 = ((const float4*)bias)[2 * f];
        float4 b1 = ((const float4*)bias)[2 * f + 1];
        float4 o0, o1;
        o0.x = fmaxf(fmaf(din, a[0] + bf_lo(sp.x), b0.x), 0.f);
        o0.y = fmaxf(fmaf(din, a[1] + bf_hi(sp.x), b0.y), 0.f);
        o0.z = fmaxf(fmaf(din, a[2] + bf_lo(sp.y), b0.z), 0.f);
        o0.w = fmaxf(fmaf(din, a[3] + bf_hi(sp.y), b0.w), 0.f);
        o1.x = fmaxf(fmaf(din, a[4] + bf_lo(sp.z), b1.x), 0.f);
        o1.y = fmaxf(fmaf(din, a[5] + bf_hi(sp.z), b1.y), 0.f);
        o1.z = fmaxf(fmaf(din, a[6] + bf_lo(sp.w), b1.z), 0.f);
        o1.w = fmaxf(fmaf(din, a[7] + bf_hi(sp.w), b1.w), 0.f);
        ((float4*)(OUT + (size_t)n * NF))[2 * f] = o0;
        ((float4*)(OUT + (size_t)n * NF))[2 * f + 1] = o1;
    }
}

// Layer-2 gather fused with mean-pool + final linear (sliced atomics).
__global__ __launch_bounds__(256, 4) void k_gatherpool(const unsigned short* __restrict__ G,
                                                       const int* __restrict__ off,
                                                       const int* __restrict__ dg,
                                                       const unsigned short* __restrict__ csrc,
                                                       const float* __restrict__ dinv,
                                                       const float* __restrict__ bias,
                                                       const void* __restrict__ batch,
                                                       const float* __restrict__ Wl,
                                                       const float* __restrict__ cntinv,
                                                       float* __restrict__ outacc) {
    __shared__ float sWl2[8 * NC * 16];  // [j][c][f], 5 KB, conflict-free reads
    __shared__ unsigned short lsbuf[4][MAXD];
    int tid = threadIdx.x;
    for (int i = tid; i < 8 * NC * 16; i += 256) {
        int j = i / (NC * 16);
        int r = i - j * (NC * 16);
        int c = r >> 4, f0 = r & 15;
        sWl2[i] = Wl[(f0 * 8 + j) * NC + c];
    }
    int isb64 = detect64((const int*)batch, NN / 2);
    int wid = tid >> 6, lane = tid & 63;
    int q = lane >> 4, f = lane & 15;
    int n = blockIdx.x * 4 + wid;        // grid is exactly NN/4 -> always valid
    int beg = off[n], end = beg + dg[n];
    float din = dinv[n];
    float a[8] = {0.f, 0.f, 0.f, 0.f, 0.f, 0.f, 0.f, 0.f};
    __syncthreads();                     // sWl2 ready; last block-wide sync
    gacc_node(G, csrc, lsbuf[wid], beg, end, q, f, lane, a);
    int g = ld_idx(batch, n, isb64);
    uint4 sp = ((const uint4*)(G + (size_t)n * NF))[f];
    float4 b0 = ((const float4*)bias)[2 * f];
    float4 b1 = ((const float4*)bias)[2 * f + 1];
    float h[8];
    h[0] = fmaxf(fmaf(din, a[0] + bf_lo(sp.x), b0.x), 0.f);
    h[1] = fmaxf(fmaf(din, a[1] + bf_hi(sp.x), b0.y), 0.f);
    h[2] = fmaxf(fmaf(din, a[2] + bf_lo(sp.y), b0.z), 0.f);
    h[3] = fmaxf(fmaf(din, a[3] + bf_hi(sp.y), b0.w), 0.f);
    h[4] = fmaxf(fmaf(din, a[4] + bf_lo(sp.z), b1.x), 0.f);
    h[5] = fmaxf(fmaf(din, a[5] + bf_hi(sp.z), b1.y), 0.f);
    h[6] = fmaxf(fmaf(din, a[6] + bf_lo(sp.w), b1.z), 0.f);
    h[7] = fmaxf(fmaf(din, a[7] + bf_hi(sp.w), b1.w), 0.f);
    float p[NC];
#pragma unroll
    for (int c = 0; c < NC; ++c) p[c] = 0.f;
#pragma unroll
    for (int j = 0; j < 8; ++j) {
        const float* wrow = sWl2 + j * (NC * 16) + f;  // [c*16 + f]
#pragma unroll
        for (int c = 0; c < NC; ++c) p[c] = fmaf(h[j], wrow[c * 16], p[c]);
    }
#pragma unroll
    for (int c = 0; c < NC; ++c) {       // reduce over f (bits 0..3)
        p[c] += __shfl_xor(p[c], 1);
        p[c] += __shfl_xor(p[c], 2);
        p[c] += __shfl_xor(p[c], 4);
        p[c] += __shfl_xor(p[c], 8);
    }
    if (lane == 0) {                     // 10 atomics into this block's slice
        float ci = cntinv[g];
        float* dst = outacc + (size_t)(blockIdx.x & (NSL - 1)) * NG * NC + g * NC;
#pragma unroll
        for (int c = 0; c < NC; ++c) atomicAdd(dst + c, p[c] * ci);
    }
}

// Epilogue: out = sum_slices(outacc) + bl (stream-order visibility).
__global__ __launch_bounds__(256) void k_fin(const float* __restrict__ outacc,
                                             const float* __restrict__ bl,
                                             float* __restrict__ out) {
    int tid = threadIdx.x;
    for (int i = tid; i < NG * NC; i += 256) {
        float s = 0.f;
#pragma unroll 8
        for (int sl = 0; sl < NSL; ++sl) s += outacc[(size_t)sl * NG * NC + i];
        out[i] = s + bl[i % NC];
    }
}

extern "C" void kernel_launch(void* const* d_in, const int* in_sizes, int n_in,
                              void* d_out, int out_size, void* d_ws, size_t ws_size,
                              hipStream_t stream) {
    const float* x  = (const float*)d_in[0];
    const void*  ei = d_in[1];
    const void*  bt = d_in[2];
    const float* W1 = (const float*)d_in[3];
    const float* b1 = (const float*)d_in[4];
    const float* W2 = (const float*)d_in[5];
    const float* b2 = (const float*)d_in[6];
    const float* Wl = (const float*)d_in[7];
    const float* bl = (const float*)d_in[8];

    char* ws = (char*)d_ws;
    int*            coff   = (int*)(ws + 0);
    int*            deg    = (int*)(ws + 40000);
    float*          dinv   = (float*)(ws + 80000);
    float*          outacc = (float*)(ws + 120000);   // 64 slices x 640 f32
    float*          cntinv = (float*)(ws + 283840);
    unsigned short* csrc   = (unsigned short*)(ws + 284160);
    unsigned short* Gb     = (unsigned short*)(ws + 2201088); // aliases bh (dead after csr)
    float*          bufB   = (float*)(ws + 4761088);          // aliases ebuf (dead after csr)
    int*            bh     = (int*)(ws + 2201088);
    int*            ebuf   = (int*)(ws + 4761088);

    k_prep<<<G1, 256, 0, stream>>>(ei, bt, bh, ebuf, outacc, cntinv);
    k_csr <<<NB, 256, 0, stream>>>(ebuf, bh, coff, deg, dinv, csrc);

    k_gemm<<<(NN + TMR - 1) / TMR, 256, 0, stream>>>(x, W1, dinv, Gb, NN);
    k_gather<<<(NN + 3) / 4, 256, 0, stream>>>(Gb, coff, deg, csrc, dinv, b1, bufB);
    k_gemm<<<(NN + TMR - 1) / TMR, 256, 0, stream>>>(bufB, W2, dinv, Gb, NN);
    k_gatherpool<<<(NN + 3) / 4, 256, 0, stream>>>(Gb, coff, deg, csrc, dinv, b2,
                                                   bt, Wl, cntinv, outacc);
    k_fin<<<1, 256, 0, stream>>>(outacc, bl, (float*)d_out);
}

// Round 8
// 159.925 us; speedup vs baseline: 2.0786x; 1.0376x over previous
//
#include <hip/hip_runtime.h>

#define NN 10000     // nodes
#define NE 640000    // edges
#define NG 64        // graphs
#define NF 128       // feature dim (both layers)
#define NC 10        // classes
#define TMR 16       // gemm row tile
#define TKC 32       // gemm k chunk
#define NB 250       // dst buckets (40 nodes each)
#define BSZ 40       // nodes per bucket
#define G1 512       // prep blocks (edge chunks)
#define GEMMB ((NN + TMR - 1) / TMR)   // 625 gemm blocks
#define ECHUNK 1250  // edges per prep block (G1*ECHUNK == NE)
#define CAP 32       // ebuf slots per (bucket, block); mean 5, P(>32) ~ 5e-12
#define CCAP 3072    // csrc entries per bucket; mean 2560 (sigma~51), +10 sigma
#define NSL 64       // outacc slices (atomic-contention spreading)
#define MAXD 192     // per-wave LDS csrc staging capacity (deg mean 64, +16 sigma)

// ---------------- ws layout (bytes) ----------------
// 0        coff    (10000 int)            40000
// 40000    deg     (10000 int)            40000
// 80000    dinv    (10000 f32)            40000
// 120000   outacc  (64 slices x 640 f32)  163840
// 283840   cntinv  (64 f32)               256
// 284160   csrc    (250*3072 ushort)      1536000  -> ends 1820160
// 1820160  bh      (250*512 int)          524288   -> ends 2344448
// 2344448  Gb      (10000*128 bf16)       2560000  -> ends 4904448  [no longer aliases bh!]
// 4904448  ebuf    (128000*32 int, 16.4MB) | bufB (10000*128 f32) [ebuf dead after csr]
//
// Round-1: device atomics = ~32B RMW past XCD L2 -> reduce in registers 1st.
// Round-2: per-block fences+done-counter = L2 flush storm -> zero fences.
// Round-3/5: gatherpool was atomic-bound, NOT gather-core-bound.
// Round-6: slicing outacc (64x) fixed contention -> all kernels < 42us.
// Round-7: LDS-staged gather indices + 1-pass csr: -6us. Occupancy counters
// show gathers are NOT resource-capped -> remaining cost is chain-shaped.
// Round-8: BREAK THE FALSE DEPENDENCY csr->gemm1: gemm1 only needed dinv
// for its epilogue. Fuse gemm1 (unscaled h) into k_prep as blocks 512..1136
// (reads x/W1 only -> runs concurrently with edge bucketing); layer-1
// gather applies dinv[src] per edge from an LDS-staged value and dinv^2 on
// the self term. 7 -> 6 launches; gemm1 fully hidden.

__device__ __forceinline__ unsigned short f2bf(float f) {   // RNE
    unsigned int u = __float_as_uint(f);
    return (unsigned short)((u + 0x7FFF + ((u >> 16) & 1)) >> 16);
}
__device__ __forceinline__ float bf_lo(unsigned int p) {
    return __uint_as_float(p << 16);
}
__device__ __forceinline__ float bf_hi(unsigned int p) {
    return __uint_as_float(p & 0xFFFF0000u);
}

// Wave-uniform detection of int64 vs int32 index buffers.
__device__ __forceinline__ int detect64(const int* w, long span) {
    int lane = threadIdx.x & 63;
    long e = (long)lane * (span - 1) / 63;
    return (__ballot(w[2 * e + 1] != 0) == 0ULL) ? 1 : 0;
}

__device__ __forceinline__ int ld_idx(const void* p, long i, int is64) {
    return is64 ? (int)((const long long*)p)[i] : ((const int*)p)[i];
}

// Heterogeneous fused kernel. Blocks [0, G1): edge hist+scatter (single
// pass, indices cached in registers); block 0 zeroes sliced outacc, block 8
// computes cntinv. Blocks [G1, G1+GEMMB): gemm1 tiles Y = bf16(X @ W1),
// UNSCALED (no dinv dependency -> fully concurrent with prep).
__global__ __launch_bounds__(256) void k_prepgemm(const void* __restrict__ ei,
                                                  const void* __restrict__ batch,
                                                  int* __restrict__ bh,
                                                  int* __restrict__ ebuf,
                                                  float* __restrict__ outacc,
                                                  float* __restrict__ cntinv,
                                                  const float* __restrict__ X,
                                                  const float* __restrict__ W,
                                                  unsigned short* __restrict__ Y) {
    __shared__ int hist[256];
    __shared__ int cur[256];
    __shared__ float sX[TKC * 20];       // [k][m] stride 20
    __shared__ float sW[32 * 132];
    int tid = threadIdx.x;

    if (blockIdx.x >= G1) {              // ---- gemm1 tile (unscaled) ----
        int m0 = (int)(blockIdx.x - G1) * TMR;
        int rg = tid & 7;                // rows rg*2, rg*2+1
        int cg = tid >> 3;               // cols cg*4 .. cg*4+3
        float acc[2][4] = {{0.f}};
        for (int kc = 0; kc < NF / TKC; ++kc) {
            int k0 = kc * TKC;
            if (tid < 128) {
                int row = tid >> 3, kq = tid & 7;
                int mm = m0 + row; if (mm > NN - 1) mm = NN - 1;
                float4 v = *(const float4*)(X + (size_t)mm * NF + k0 + kq * 4);
                sX[(kq * 4 + 0) * 20 + row] = v.x;
                sX[(kq * 4 + 1) * 20 + row] = v.y;
                sX[(kq * 4 + 2) * 20 + row] = v.z;
                sX[(kq * 4 + 3) * 20 + row] = v.w;
            }
#pragma unroll
            for (int j = 0; j < 4; ++j) {
                int idx = tid + 256 * j;
                int k = idx >> 5, cq = idx & 31;
                float4 v = *(const float4*)(W + (size_t)(k0 + k) * NF + cq * 4);
                *(float4*)(sW + cq * 132 + k * 4) = v;
            }
            __syncthreads();
#pragma unroll 8
            for (int k = 0; k < TKC; ++k) {
                float2 xf = *(const float2*)(sX + k * 20 + rg * 2);
                float4 wf = *(const float4*)(sW + cg * 132 + k * 4);
                acc[0][0] = fmaf(xf.x, wf.x, acc[0][0]);
                acc[0][1] = fmaf(xf.x, wf.y, acc[0][1]);
                acc[0][2] = fmaf(xf.x, wf.z, acc[0][2]);
                acc[0][3] = fmaf(xf.x, wf.w, acc[0][3]);
                acc[1][0] = fmaf(xf.y, wf.x, acc[1][0]);
                acc[1][1] = fmaf(xf.y, wf.y, acc[1][1]);
                acc[1][2] = fmaf(xf.y, wf.z, acc[1][2]);
                acc[1][3] = fmaf(xf.y, wf.w, acc[1][3]);
            }
            __syncthreads();
        }
#pragma unroll
        for (int r = 0; r < 2; ++r) {
            int m = m0 + rg * 2 + r;
            if (m < NN) {
                ushort4 h;
                h.x = f2bf(acc[r][0]);
                h.y = f2bf(acc[r][1]);
                h.z = f2bf(acc[r][2]);
                h.w = f2bf(acc[r][3]);
                *(ushort4*)(Y + (size_t)m * NF + cg * 4) = h;
            }
        }
        return;
    }

    // ---- prep (edge hist + scatter) ----
    int is64 = detect64((const int*)ei, NE);
    hist[tid] = 0;
    __syncthreads();
    if (blockIdx.x == 0) {
        for (int i = tid; i < NSL * NG * NC; i += 256) outacc[i] = 0.f;
    }
    if (blockIdx.x == 8 && tid < NG) {
        int isb = detect64((const int*)batch, NN / 2);
        int lo0 = 0, hi0 = NN;
        while (lo0 < hi0) {
            int m = (lo0 + hi0) >> 1;
            if (ld_idx(batch, m, isb) < tid) lo0 = m + 1; else hi0 = m;
        }
        int lo1 = lo0, hi1 = NN;
        while (lo1 < hi1) {
            int m = (lo1 + hi1) >> 1;
            if (ld_idx(batch, m, isb) < tid + 1) lo1 = m + 1; else hi1 = m;
        }
        cntinv[tid] = 1.0f / fmaxf((float)(lo1 - lo0), 1.0f);
    }
    int e0 = blockIdx.x * ECHUNK;
    int dstv[5], srcv[5];
#pragma unroll
    for (int i = 0; i < 5; ++i) {
        int r = tid + i * 256;
        if (r < ECHUNK) {
            long e = (long)e0 + r;
            dstv[i] = ld_idx(ei, (long)NE + e, is64);
            srcv[i] = ld_idx(ei, e, is64);
            atomicAdd(&hist[dstv[i] / BSZ], 1);
        } else {
            dstv[i] = -1; srcv[i] = 0;
        }
    }
    __syncthreads();
    if (tid < NB) {
        bh[tid * G1 + blockIdx.x] = min(hist[tid], CAP);
        cur[tid] = (tid * G1 + blockIdx.x) * CAP;
    }
    __syncthreads();
#pragma unroll
    for (int i = 0; i < 5; ++i) {
        if (tid + i * 256 < ECHUNK) {
            int dst = dstv[i], src = srcv[i];
            int b = dst / BSZ;
            int p = atomicAdd(&cur[b], 1);
            int lim = (b * G1 + blockIdx.x) * CAP + CAP;
            if (p < lim) ebuf[p] = ((dst - b * BSZ) << 14) | src;
        }
    }
}

// One block per bucket, single global pass (unchanged from round 7).
__global__ __launch_bounds__(256) void k_csr(const int* __restrict__ ebuf,
                                             const int* __restrict__ bh,
                                             int* __restrict__ coff,
                                             int* __restrict__ deg,
                                             float* __restrict__ dinv,
                                             unsigned short* __restrict__ csrc) {
    __shared__ int scnt[G1];
    __shared__ int cbase[G1];
    __shared__ int wsum[4];
    __shared__ int eb[CCAP];
    __shared__ int dcount[BSZ];
    __shared__ int cur[BSZ];
    int b = blockIdx.x, tid = threadIdx.x;
    int lane = tid & 63, wv = tid >> 6;
    for (int i = tid; i < G1; i += 256) scnt[i] = bh[b * G1 + i];
    if (tid < BSZ) dcount[tid] = 0;
    __syncthreads();
    int v0 = scnt[2 * tid], v1 = scnt[2 * tid + 1];
    int lsum = v0 + v1;
    int pref = lsum;
    for (int o = 1; o < 64; o <<= 1) {
        int t = __shfl_up(pref, o, 64);
        if (lane >= o) pref += t;
    }
    if (lane == 63) wsum[wv] = pref;
    __syncthreads();
    int off = 0;
#pragma unroll
    for (int j = 0; j < 4; ++j) if (j < wv) off += wsum[j];
    int ex = pref - lsum + off;
    cbase[2 * tid] = ex;
    cbase[2 * tid + 1] = ex + v0;
    int tot = wsum[0] + wsum[1] + wsum[2] + wsum[3];
    if (tot > CCAP) tot = CCAP;
    __syncthreads();
#pragma unroll
    for (int cp = 0; cp < 2; ++cp) {
        int cell = 2 * tid + cp;
        int c = scnt[cell], lb = cbase[cell];
        int gb = (b * G1 + cell) * CAP;
        if (lb + c > CCAP) c = max(0, CCAP - lb);
        for (int i = 0; i < c; ++i) eb[lb + i] = ebuf[gb + i];
    }
    __syncthreads();
    for (int i = tid; i < tot; i += 256)
        atomicAdd(&dcount[eb[i] >> 14], 1);
    __syncthreads();
    if (tid < 64) {
        int d = (tid < BSZ) ? dcount[tid] : 0;
        int pr = d;
        for (int o = 1; o < 64; o <<= 1) {
            int t = __shfl_up(pr, o, 64);
            if (tid >= o) pr += t;
        }
        if (tid < BSZ) {
            int st = pr - d;
            cur[tid] = b * CCAP + st;
            coff[b * BSZ + tid] = b * CCAP + st;
            deg[b * BSZ + tid] = d;
            dinv[b * BSZ + tid] = rsqrtf((float)d + 1.0f);
        }
    }
    __syncthreads();
    for (int i = tid; i < tot; i += 256) {
        int pk = eb[i];
        int p = atomicAdd(&cur[pk >> 14], 1);
        csrc[p] = (unsigned short)(pk & 16383);
    }
}

// Standalone gemm (layer 2 only): Y(bf16) = (X @ W) * dinv[row].
__global__ __launch_bounds__(256) void k_gemm(const float* __restrict__ X,
                                              const float* __restrict__ W,
                                              const float* __restrict__ dinv,
                                              unsigned short* __restrict__ Y,
                                              int nrows) {
    __shared__ float sX[TKC * 20];
    __shared__ float sW[32 * 132];
    int tid = threadIdx.x;
    int rg = tid & 7;
    int cg = tid >> 3;
    int m0 = blockIdx.x * TMR;
    float acc[2][4] = {{0.f}};
    for (int kc = 0; kc < NF / TKC; ++kc) {
        int k0 = kc * TKC;
        if (tid < 128) {
            int row = tid >> 3, kq = tid & 7;
            int mm = m0 + row; if (mm > nrows - 1) mm = nrows - 1;
            float4 v = *(const float4*)(X + (size_t)mm * NF + k0 + kq * 4);
            sX[(kq * 4 + 0) * 20 + row] = v.x;
            sX[(kq * 4 + 1) * 20 + row] = v.y;
            sX[(kq * 4 + 2) * 20 + row] = v.z;
            sX[(kq * 4 + 3) * 20 + row] = v.w;
        }
#pragma unroll
        for (int j = 0; j < 4; ++j) {
            int idx = tid + 256 * j;
            int k = idx >> 5, cq = idx & 31;
            float4 v = *(const float4*)(W + (size_t)(k0 + k) * NF + cq * 4);
            *(float4*)(sW + cq * 132 + k * 4) = v;
        }
        __syncthreads();
#pragma unroll 8
        for (int k = 0; k < TKC; ++k) {
            float2 xf = *(const float2*)(sX + k * 20 + rg * 2);
            float4 wf = *(const float4*)(sW + cg * 132 + k * 4);
            acc[0][0] = fmaf(xf.x, wf.x, acc[0][0]);
            acc[0][1] = fmaf(xf.x, wf.y, acc[0][1]);
            acc[0][2] = fmaf(xf.x, wf.z, acc[0][2]);
            acc[0][3] = fmaf(xf.x, wf.w, acc[0][3]);
            acc[1][0] = fmaf(xf.y, wf.x, acc[1][0]);
            acc[1][1] = fmaf(xf.y, wf.y, acc[1][1]);
            acc[1][2] = fmaf(xf.y, wf.z, acc[1][2]);
            acc[1][3] = fmaf(xf.y, wf.w, acc[1][3]);
        }
        __syncthreads();
    }
#pragma unroll
    for (int r = 0; r < 2; ++r) {
        int m = m0 + rg * 2 + r;
        if (m < nrows) {
            float ds = dinv[m];
            ushort4 h;
            h.x = f2bf(acc[r][0] * ds);
            h.y = f2bf(acc[r][1] * ds);
            h.z = f2bf(acc[r][2] * ds);
            h.w = f2bf(acc[r][3] * ds);
            *(ushort4*)(Y + (size_t)m * NF + cg * 4) = h;
        }
    }
}

// Gather core, LDS-staged indices (+ optionally per-edge dinv values when
// the G rows are unscaled). One wave per node; quarter-wave (16 lanes x
// uint4) per edge; 8 independent row loads in flight. Broadcast LDS reads
// (conflict-free). After the xor16/32 shuffles ALL lanes hold the sums:
//   EDGE_SCALE=1: a = sum_e dinv[src_e] * h[src_e]   (h unscaled)
//   EDGE_SCALE=0: a = sum_e g[src_e]                 (g pre-scaled)
template <int EDGE_SCALE>
__device__ __forceinline__ void gacc_node(const unsigned short* __restrict__ G,
                                          const unsigned short* __restrict__ csrc,
                                          const float* __restrict__ dv,
                                          unsigned short* ls, float* lsd,
                                          int beg, int end, int q, int f, int lane,
                                          float a[8]) {
    int dg = end - beg;
    int nst = min(dg, MAXD);
    for (int i = lane; i < nst; i += 64) {
        unsigned short s = csrc[beg + i];
        ls[i] = s;
        if (EDGE_SCALE) lsd[i] = dv[s];
    }
    int vi = q;
    int nfull = nst & ~31;
    for (; vi < nfull; vi += 32) {
        int s[8]; float d[8];
#pragma unroll
        for (int j = 0; j < 8; ++j) {
            s[j] = ls[vi + 4 * j];
            d[j] = EDGE_SCALE ? lsd[vi + 4 * j] : 1.f;
        }
        uint4 p[8];
#pragma unroll
        for (int j = 0; j < 8; ++j)
            p[j] = ((const uint4*)(G + (size_t)s[j] * NF))[f];
#pragma unroll
        for (int j = 0; j < 8; ++j) {
            if (EDGE_SCALE) {
                a[0] = fmaf(d[j], bf_lo(p[j].x), a[0]); a[1] = fmaf(d[j], bf_hi(p[j].x), a[1]);
                a[2] = fmaf(d[j], bf_lo(p[j].y), a[2]); a[3] = fmaf(d[j], bf_hi(p[j].y), a[3]);
                a[4] = fmaf(d[j], bf_lo(p[j].z), a[4]); a[5] = fmaf(d[j], bf_hi(p[j].z), a[5]);
                a[6] = fmaf(d[j], bf_lo(p[j].w), a[6]); a[7] = fmaf(d[j], bf_hi(p[j].w), a[7]);
            } else {
                a[0] += bf_lo(p[j].x); a[1] += bf_hi(p[j].x);
                a[2] += bf_lo(p[j].y); a[3] += bf_hi(p[j].y);
                a[4] += bf_lo(p[j].z); a[5] += bf_hi(p[j].z);
                a[6] += bf_lo(p[j].w); a[7] += bf_hi(p[j].w);
            }
        }
    }
    int nfull16 = nst & ~15;
    for (; vi < nfull16; vi += 16) {
        int s[4]; float d[4];
#pragma unroll
        for (int j = 0; j < 4; ++j) {
            s[j] = ls[vi + 4 * j];
            d[j] = EDGE_SCALE ? lsd[vi + 4 * j] : 1.f;
        }
        uint4 p[4];
#pragma unroll
        for (int j = 0; j < 4; ++j)
            p[j] = ((const uint4*)(G + (size_t)s[j] * NF))[f];
#pragma unroll
        for (int j = 0; j < 4; ++j) {
            if (EDGE_SCALE) {
                a[0] = fmaf(d[j], bf_lo(p[j].x), a[0]); a[1] = fmaf(d[j], bf_hi(p[j].x), a[1]);
                a[2] = fmaf(d[j], bf_lo(p[j].y), a[2]); a[3] = fmaf(d[j], bf_hi(p[j].y), a[3]);
                a[4] = fmaf(d[j], bf_lo(p[j].z), a[4]); a[5] = fmaf(d[j], bf_hi(p[j].z), a[5]);
                a[6] = fmaf(d[j], bf_lo(p[j].w), a[6]); a[7] = fmaf(d[j], bf_hi(p[j].w), a[7]);
            } else {
                a[0] += bf_lo(p[j].x); a[1] += bf_hi(p[j].x);
                a[2] += bf_lo(p[j].y); a[3] += bf_hi(p[j].y);
                a[4] += bf_lo(p[j].z); a[5] += bf_hi(p[j].z);
                a[6] += bf_lo(p[j].w); a[7] += bf_hi(p[j].w);
            }
        }
    }
    int npad = (nst + 3) & ~3;
    for (; vi < npad; vi += 4) {         // predicated tail, uniform trips
        int ii = min(vi, nst - 1);
        int s = ls[ii];
        float d = EDGE_SCALE ? lsd[ii] : 1.f;
        uint4 p = ((const uint4*)(G + (size_t)s * NF))[f];
        if (vi < nst) {
            if (EDGE_SCALE) {
                a[0] = fmaf(d, bf_lo(p.x), a[0]); a[1] = fmaf(d, bf_hi(p.x), a[1]);
                a[2] = fmaf(d, bf_lo(p.y), a[2]); a[3] = fmaf(d, bf_hi(p.y), a[3]);
                a[4] = fmaf(d, bf_lo(p.z), a[4]); a[5] = fmaf(d, bf_hi(p.z), a[5]);
                a[6] = fmaf(d, bf_lo(p.w), a[6]); a[7] = fmaf(d, bf_hi(p.w), a[7]);
            } else {
                a[0] += bf_lo(p.x); a[1] += bf_hi(p.x);
                a[2] += bf_lo(p.y); a[3] += bf_hi(p.y);
                a[4] += bf_lo(p.z); a[5] += bf_hi(p.z);
                a[6] += bf_lo(p.w); a[7] += bf_hi(p.w);
            }
        }
    }
    for (int e2 = beg + MAXD + q; e2 < end; e2 += 4) {  // deg>MAXD fallback
        int s = csrc[e2];
        float d = EDGE_SCALE ? dv[s] : 1.f;
        uint4 p = ((const uint4*)(G + (size_t)s * NF))[f];
        if (EDGE_SCALE) {
            a[0] = fmaf(d, bf_lo(p.x), a[0]); a[1] = fmaf(d, bf_hi(p.x), a[1]);
            a[2] = fmaf(d, bf_lo(p.y), a[2]); a[3] = fmaf(d, bf_hi(p.y), a[3]);
            a[4] = fmaf(d, bf_lo(p.z), a[4]); a[5] = fmaf(d, bf_hi(p.z), a[5]);
            a[6] = fmaf(d, bf_lo(p.w), a[6]); a[7] = fmaf(d, bf_hi(p.w), a[7]);
        } else {
            a[0] += bf_lo(p.x); a[1] += bf_hi(p.x);
            a[2] += bf_lo(p.y); a[3] += bf_hi(p.y);
            a[4] += bf_lo(p.z); a[5] += bf_hi(p.z);
            a[6] += bf_lo(p.w); a[7] += bf_hi(p.w);
        }
    }
#pragma unroll
    for (int j = 0; j < 8; ++j) a[j] += __shfl_xor(a[j], 16);
#pragma unroll
    for (int j = 0; j < 8; ++j) a[j] += __shfl_xor(a[j], 32);
}

// Layer-1 gather over UNSCALED h:
// OUT[n] = relu( dinv[n]*( sum_e dinv[s]h[s] + dinv[n]h[n] ) + bias ).
__global__ __launch_bounds__(256, 4) void k_gather(const unsigned short* __restrict__ G,
                                                   const int* __restrict__ off,
                                                   const int* __restrict__ dg,
                                                   const unsigned short* __restrict__ csrc,
                                                   const float* __restrict__ dinv,
                                                   const float* __restrict__ bias,
                                                   float* __restrict__ OUT) {
    __shared__ unsigned short lsbuf[4][MAXD];
    __shared__ float lsdbuf[4][MAXD];
    int wid = threadIdx.x >> 6, lane = threadIdx.x & 63;
    int q = lane >> 4, f = lane & 15;
    int n = blockIdx.x * 4 + wid;
    if (n >= NN) return;
    int beg = off[n], end = beg + dg[n];
    float din = dinv[n];
    float a[8] = {0.f, 0.f, 0.f, 0.f, 0.f, 0.f, 0.f, 0.f};
    gacc_node<1>(G, csrc, dinv, lsbuf[wid], lsdbuf[wid], beg, end, q, f, lane, a);
    if (q == 0) {
        uint4 sp = ((const uint4*)(G + (size_t)n * NF))[f];
        float4 b0 = ((const float4*)bias)[2 * f];
        float4 b1 = ((const float4*)bias)[2 * f + 1];
        float4 o0, o1;
        o0.x = fmaxf(fmaf(din, fmaf(din, bf_lo(sp.x), a[0]), b0.x), 0.f);
        o0.y = fmaxf(fmaf(din, fmaf(din, bf_hi(sp.x), a[1]), b0.y), 0.f);
        o0.z = fmaxf(fmaf(din, fmaf(din, bf_lo(sp.y), a[2]), b0.z), 0.f);
        o0.w = fmaxf(fmaf(din, fmaf(din, bf_hi(sp.y), a[3]), b0.w), 0.f);
        o1.x = fmaxf(fmaf(din, fmaf(din, bf_lo(sp.z), a[4]), b1.x), 0.f);
        o1.y = fmaxf(fmaf(din, fmaf(din, bf_hi(sp.z), a[5]), b1.y), 0.f);
        o1.z = fmaxf(fmaf(din, fmaf(din, bf_lo(sp.w), a[6]), b1.z), 0.f);
        o1.w = fmaxf(fmaf(din, fmaf(din, bf_hi(sp.w), a[7]), b1.w), 0.f);
        ((float4*)(OUT + (size_t)n * NF))[2 * f] = o0;
        ((float4*)(OUT + (size_t)n * NF))[2 * f + 1] = o1;
    }
}

// Layer-2 gather fused with mean-pool + final linear (sliced atomics;
// G rows pre-scaled by gemm2 -> EDGE_SCALE=0).
__global__ __launch_bounds__(256, 4) void k_gatherpool(const unsigned short* __restrict__ G,
                                                       const int* __restrict__ off,
                                                       const int* __restrict__ dg,
                                                       const unsigned short* __restrict__ csrc,
                                                       const float* __restrict__ dinv,
                                                       const float* __restrict__ bias,
                                                       const void* __restrict__ batch,
                                                       const float* __restrict__ Wl,
                                                       const float* __restrict__ cntinv,
                                                       float* __restrict__ outacc) {
    __shared__ float sWl2[8 * NC * 16];  // [j][c][f], conflict-free reads
    __shared__ unsigned short lsbuf[4][MAXD];
    int tid = threadIdx.x;
    for (int i = tid; i < 8 * NC * 16; i += 256) {
        int j = i / (NC * 16);
        int r = i - j * (NC * 16);
        int c = r >> 4, f0 = r & 15;
        sWl2[i] = Wl[(f0 * 8 + j) * NC + c];
    }
    int isb64 = detect64((const int*)batch, NN / 2);
    int wid = tid >> 6, lane = tid & 63;
    int q = lane >> 4, f = lane & 15;
    int n = blockIdx.x * 4 + wid;        // grid is exactly NN/4 -> always valid
    int beg = off[n], end = beg + dg[n];
    float din = dinv[n];
    float a[8] = {0.f, 0.f, 0.f, 0.f, 0.f, 0.f, 0.f, 0.f};
    __syncthreads();                     // sWl2 ready; last block-wide sync
    gacc_node<0>(G, csrc, dinv, lsbuf[wid], (float*)nullptr, beg, end, q, f, lane, a);
    int g = ld_idx(batch, n, isb64);
    uint4 sp = ((const uint4*)(G + (size_t)n * NF))[f];
    float4 b0 = ((const float4*)bias)[2 * f];
    float4 b1 = ((const float4*)bias)[2 * f + 1];
    float h[8];
    h[0] = fmaxf(fmaf(din, a[0] + bf_lo(sp.x), b0.x), 0.f);
    h[1] = fmaxf(fmaf(din, a[1] + bf_hi(sp.x), b0.y), 0.f);
    h[2] = fmaxf(fmaf(din, a[2] + bf_lo(sp.y), b0.z), 0.f);
    h[3] = fmaxf(fmaf(din, a[3] + bf_hi(sp.y), b0.w), 0.f);
    h[4] = fmaxf(fmaf(din, a[4] + bf_lo(sp.z), b1.x), 0.f);
    h[5] = fmaxf(fmaf(din, a[5] + bf_hi(sp.z), b1.y), 0.f);
    h[6] = fmaxf(fmaf(din, a[6] + bf_lo(sp.w), b1.z), 0.f);
    h[7] = fmaxf(fmaf(din, a[7] + bf_hi(sp.w), b1.w), 0.f);
    float p[NC];
#pragma unroll
    for (int c = 0; c < NC; ++c) p[c] = 0.f;
#pragma unroll
    for (int j = 0; j < 8; ++j) {
        const float* wrow = sWl2 + j * (NC * 16) + f;  // [c*16 + f]
#pragma unroll
        for (int c = 0; c < NC; ++c) p[c] = fmaf(h[j], wrow[c * 16], p[c]);
    }
#pragma unroll
    for (int c = 0; c < NC; ++c) {       // reduce over f (bits 0..3)
        p[c] += __shfl_xor(p[c], 1);
        p[c] += __shfl_xor(p[c], 2);
        p[c] += __shfl_xor(p[c], 4);
        p[c] += __shfl_xor(p[c], 8);
    }
    if (lane == 0) {                     // 10 atomics into this block's slice
        float ci = cntinv[g];
        float* dst = outacc + (size_t)(blockIdx.x & (NSL - 1)) * NG * NC + g * NC;
#pragma unroll
        for (int c = 0; c < NC; ++c) atomicAdd(dst + c, p[c] * ci);
    }
}

// Epilogue: out = sum_slices(outacc) + bl (stream-order visibility).
__global__ __launch_bounds__(256) void k_fin(const float* __restrict__ outacc,
                                             const float* __restrict__ bl,
                                             float* __restrict__ out) {
    int tid = threadIdx.x;
    for (int i = tid; i < NG * NC; i += 256) {
        float s = 0.f;
#pragma unroll 8
        for (int sl = 0; sl < NSL; ++sl) s += outacc[(size_t)sl * NG * NC + i];
        out[i] = s + bl[i % NC];
    }
}

extern "C" void kernel_launch(void* const* d_in, const int* in_sizes, int n_in,
                              void* d_out, int out_size, void* d_ws, size_t ws_size,
                              hipStream_t stream) {
    const float* x  = (const float*)d_in[0];
    const void*  ei = d_in[1];
    const void*  bt = d_in[2];
    const float* W1 = (const float*)d_in[3];
    const float* b1 = (const float*)d_in[4];
    const float* W2 = (const float*)d_in[5];
    const float* b2 = (const float*)d_in[6];
    const float* Wl = (const float*)d_in[7];
    const float* bl = (const float*)d_in[8];

    char* ws = (char*)d_ws;
    int*            coff   = (int*)(ws + 0);
    int*            deg    = (int*)(ws + 40000);
    float*          dinv   = (float*)(ws + 80000);
    float*          outacc = (float*)(ws + 120000);   // 64 slices x 640 f32
    float*          cntinv = (float*)(ws + 283840);
    unsigned short* csrc   = (unsigned short*)(ws + 284160);
    int*            bh     = (int*)(ws + 1820160);
    unsigned short* Gb     = (unsigned short*)(ws + 2344448); // own region now
    int*            ebuf   = (int*)(ws + 4904448);
    float*          bufB   = (float*)(ws + 4904448); // aliases ebuf (dead after csr)

    k_prepgemm<<<G1 + GEMMB, 256, 0, stream>>>(ei, bt, bh, ebuf, outacc, cntinv,
                                               x, W1, Gb);
    k_csr <<<NB, 256, 0, stream>>>(ebuf, bh, coff, deg, dinv, csrc);

    k_gather<<<(NN + 3) / 4, 256, 0, stream>>>(Gb, coff, deg, csrc, dinv, b1, bufB);
    k_gemm<<<GEMMB, 256, 0, stream>>>(bufB, W2, dinv, Gb, NN);
    k_gatherpool<<<(NN + 3) / 4, 256, 0, stream>>>(Gb, coff, deg, csrc, dinv, b2,
                                                   bt, Wl, cntinv, outacc);
    k_fin<<<1, 256, 0, stream>>>(outacc, bl, (float*)d_out);
}